// Round 1
// baseline (5282.329 us; speedup 1.0000x reference)
//
#include <hip/hip_runtime.h>
#include <hip/hip_bf16.h>

// Problem constants (B=1)
#define S_LEN   2048
#define NH      16
#define ROPE_D  64
#define IDIM    128
#define KV_LORA 512
#define TOPK_K  1024
#define SCALING 0.08838834764831845f   // 128^-0.5

// ---------------------------------------------------------------------------
// Generic fp32 tiled GEMM: C = A @ B^T   (A: MxK row-major, B: NxK row-major)
// with batch strides (grid.z). 64x64 tile, BK=16, 256 thr, 4x4 micro-tile.
// ---------------------------------------------------------------------------
#define BM 64
#define BN 64
#define BK 16

__global__ __launch_bounds__(256)
void gemm_abt(const float* __restrict__ A, const float* __restrict__ B,
              float* __restrict__ C,
              int M, int N, int K, int lda, int ldb, int ldc,
              long strideA, long strideB, long strideC)
{
    int bz = blockIdx.z;
    A += bz * strideA; B += bz * strideB; C += bz * strideC;
    __shared__ float As[BK][BM + 1];
    __shared__ float Bs[BK][BN + 1];
    int tid = threadIdx.x;
    int tx = tid & 15, ty = tid >> 4;
    int m0 = blockIdx.y * BM, n0 = blockIdx.x * BN;
    float acc[4][4] = {};
    for (int k0 = 0; k0 < K; k0 += BK) {
        for (int t = tid; t < BM * BK; t += 256) {
            int m = t >> 4, kk = t & 15;
            As[kk][m] = (m0 + m < M) ? A[(long)(m0 + m) * lda + k0 + kk] : 0.f;
        }
        for (int t = tid; t < BN * BK; t += 256) {
            int nn = t >> 4, kk = t & 15;
            Bs[kk][nn] = (n0 + nn < N) ? B[(long)(n0 + nn) * ldb + k0 + kk] : 0.f;
        }
        __syncthreads();
        #pragma unroll
        for (int kk = 0; kk < BK; kk++) {
            float a[4], b[4];
            #pragma unroll
            for (int i = 0; i < 4; i++) a[i] = As[kk][ty * 4 + i];
            #pragma unroll
            for (int j = 0; j < 4; j++) b[j] = Bs[kk][tx * 4 + j];
            #pragma unroll
            for (int i = 0; i < 4; i++)
                #pragma unroll
                for (int j = 0; j < 4; j++) acc[i][j] += a[i] * b[j];
        }
        __syncthreads();
    }
    for (int i = 0; i < 4; i++) {
        int m = m0 + ty * 4 + i;
        if (m >= M) continue;
        for (int j = 0; j < 4; j++) {
            int n = n0 + tx * 4 + j;
            if (n < N) C[(long)m * ldc + n] = acc[i][j];
        }
    }
}

// ---------------------------------------------------------------------------
// w = |gemm_out + bias|   (in-place), 2048*16 elements
// ---------------------------------------------------------------------------
__global__ void absbias_inplace(float* __restrict__ w, const float* __restrict__ b)
{
    int idx = blockIdx.x * 256 + threadIdx.x;
    if (idx < S_LEN * NH) w[idx] = fabsf(w[idx] + b[idx & 15]);
}

// ---------------------------------------------------------------------------
// In-place interleaved RoPE on ql rows -> index_q.  One block (64 thr) per (s,h).
// deinterleave: y[i] = x[2i] (i<32), x[2(i-32)+1] (i>=32); out = y*cos + rot_half(y)*sin
// pass half (elements 64..127) is unchanged -> nothing to write.
// ---------------------------------------------------------------------------
__global__ void rope_iq_inplace(float* __restrict__ ql,
                                const float* __restrict__ cosb,
                                const float* __restrict__ sinb)
{
    int s = blockIdx.x, h = blockIdx.y, i = threadIdx.x;   // i in [0,64)
    float* row = ql + (long)s * (NH * IDIM) + h * IDIM;
    float y  = (i < 32) ? row[2 * i]     : row[2 * (i - 32) + 1];
    float yr = (i < 32) ? -row[2 * i + 1] : row[2 * (i - 32)];
    float c  = cosb[s * ROPE_D + i];
    float sn = sinb[s * ROPE_D + i];
    float val = y * c + yr * sn;
    __syncthreads();           // all reads done before in-place writes
    row[i] = val;
}

// ---------------------------------------------------------------------------
// In-place build of index_k from ckv rows: rot half roped, pass half rmsnorm'd.
// One block (64 thr = 1 wave) per k.
// ---------------------------------------------------------------------------
__global__ void build_ik_inplace(float* __restrict__ ckv,
                                 const float* __restrict__ cosb,
                                 const float* __restrict__ sinb,
                                 const float* __restrict__ knw)
{
    int k = blockIdx.x, i = threadIdx.x;   // i in [0,64)
    float* row = ckv + (long)k * IDIM;
    float y  = (i < 32) ? row[2 * i]     : row[2 * (i - 32) + 1];
    float yr = (i < 32) ? -row[2 * i + 1] : row[2 * (i - 32)];
    float c  = cosb[k * ROPE_D + i];
    float sn = sinb[k * ROPE_D + i];
    float rot = y * c + yr * sn;
    float xp = row[ROPE_D + i];
    float ss = xp * xp;
    for (int off = 32; off; off >>= 1) ss += __shfl_down(ss, off, 64);
    ss = __shfl(ss, 0, 64);
    float nv = xp * rsqrtf(ss / 64.f + 1e-6f) * knw[i];
    __syncthreads();
    row[i] = rot;
    row[ROPE_D + i] = nv;
}

// ---------------------------------------------------------------------------
// Indexer scores: sc[q][k] = sum_h w[q][h] * relu(SCALING * iq[q,h,:]·ik[k,:])
// 64q x 64k tile per block; only lower-triangle tiles computed.
// ---------------------------------------------------------------------------
__global__ __launch_bounds__(256)
void scores_kernel(const float* __restrict__ iq, const float* __restrict__ ik,
                   const float* __restrict__ w, float* __restrict__ sc)
{
    int bk = blockIdx.x, bq = blockIdx.y;
    if (bk > bq) return;                       // tile fully above diagonal
    int q0 = bq * 64, k0 = bk * 64;
    __shared__ float Qs[64][33];
    __shared__ float Ks[64][33];
    __shared__ float Ws[64][17];
    int tid = threadIdx.x;
    int tx = tid & 15, ty = tid >> 4;
    for (int i = tid; i < 64 * 16; i += 256)
        Ws[i >> 4][i & 15] = w[(q0 + (i >> 4)) * NH + (i & 15)];
    float fin[4][4] = {};
    for (int h = 0; h < NH; h++) {
        float acc[4][4] = {};
        for (int dc = 0; dc < 4; dc++) {
            __syncthreads();
            for (int i = tid; i < 64 * 32; i += 256) {
                int r = i >> 5, d = i & 31;
                Qs[r][d] = iq[((long)(q0 + r) * NH + h) * IDIM + dc * 32 + d];
                Ks[r][d] = ik[(long)(k0 + r) * IDIM + dc * 32 + d];
            }
            __syncthreads();
            #pragma unroll
            for (int kk = 0; kk < 32; kk++) {
                float a[4], b[4];
                #pragma unroll
                for (int i = 0; i < 4; i++) a[i] = Qs[ty * 4 + i][kk];
                #pragma unroll
                for (int j = 0; j < 4; j++) b[j] = Ks[tx * 4 + j][kk];
                #pragma unroll
                for (int i = 0; i < 4; i++)
                    #pragma unroll
                    for (int j = 0; j < 4; j++) acc[i][j] += a[i] * b[j];
            }
        }
        #pragma unroll
        for (int i = 0; i < 4; i++)
            #pragma unroll
            for (int j = 0; j < 4; j++) {
                float v = acc[i][j] * SCALING;
                v = v > 0.f ? v : 0.f;
                fin[i][j] += v * Ws[ty * 4 + i][h];
            }
    }
    for (int i = 0; i < 4; i++)
        for (int j = 0; j < 4; j++)
            sc[(long)(q0 + ty * 4 + i) * S_LEN + k0 + tx * 4 + j] = fin[i][j];
}

// ---------------------------------------------------------------------------
// Exact top-1024 per row via radix-select on float bits (scores >= 0).
// Ties broken by lowest index (matches jax.lax.top_k). One block per row.
// ---------------------------------------------------------------------------
__device__ __forceinline__ int block_scan_excl(int v, volatile int* lds, int tid, int* total)
{
    lds[tid] = v;
    __syncthreads();
    int x = v;
    for (int off = 1; off < 256; off <<= 1) {
        int y = (tid >= off) ? lds[tid - off] : 0;
        __syncthreads();
        x += y;
        lds[tid] = x;
        __syncthreads();
    }
    int t = lds[255];
    __syncthreads();
    *total = t;
    return x - v;
}

__global__ __launch_bounds__(256)
void topk_kernel(const float* __restrict__ sc, int* __restrict__ sel_idx,
                 int* __restrict__ sel_cnt)
{
    __shared__ int lds[256];
    __shared__ int wsum[4];
    int q = blockIdx.x, tid = threadIdx.x;
    int n = q + 1;
    int* row_sel = sel_idx + (long)q * TOPK_K;
    if (n <= TOPK_K) {                      // all causal keys selected
        for (int i = tid; i < n; i += 256) row_sel[i] = i;
        if (tid == 0) sel_cnt[q] = n;
        return;
    }
    const float* row = sc + (long)q * S_LEN;
    unsigned bits[8];
    int base = tid * 8;
    #pragma unroll
    for (int i = 0; i < 8; i++) {
        int k = base + i;
        bits[i] = (k < n) ? __float_as_uint(row[k]) : 0u;   // scores >= 0
    }
    unsigned prefix = 0;
    for (int bit = 30; bit >= 0; bit--) {
        unsigned cand = prefix | (1u << bit);
        int c = 0;
        #pragma unroll
        for (int i = 0; i < 8; i++) c += (bits[i] >= cand) ? 1 : 0;
        for (int off = 32; off; off >>= 1) c += __shfl_down(c, off, 64);
        if ((tid & 63) == 0) wsum[tid >> 6] = c;
        __syncthreads();
        int total = wsum[0] + wsum[1] + wsum[2] + wsum[3];
        __syncthreads();
        if (total >= TOPK_K) prefix = cand;
    }
    unsigned v = prefix;                    // exact 1024th-largest value bits
    int lgt = 0, leq = 0;
    #pragma unroll
    for (int i = 0; i < 8; i++) {
        int k = base + i;
        if (k >= n) break;
        if (bits[i] > v) lgt++;
        else if (bits[i] == v) leq++;
    }
    int tot_gt, tot_eq;
    int gt_off = block_scan_excl(lgt, lds, tid, &tot_gt);
    int eq_off = block_scan_excl(leq, lds, tid, &tot_eq);
    int fill = TOPK_K - tot_gt;             // # ties to take (lowest index first)
    int gpos = gt_off, epos = eq_off;
    for (int i = 0; i < 8; i++) {
        int k = base + i;
        if (k >= n) break;
        if (bits[i] > v) {
            row_sel[gpos++] = k;
        } else if (bits[i] == v) {
            if (epos < fill) row_sel[tot_gt + epos] = k;
            epos++;
        }
    }
    if (tid == 0) sel_cnt[q] = TOPK_K;
}

// ---------------------------------------------------------------------------
// Sparse attention per (q,h): logits over selected keys (192-dim dots via
// folded k_eff + k_rot), softmax, then out[d] = sum p_i * v_proj[k_i,h,d].
// ---------------------------------------------------------------------------
__global__ __launch_bounds__(256)
void attn_kernel(const float* __restrict__ qp, const float* __restrict__ qr,
                 const float* __restrict__ keff, const float* __restrict__ krot,
                 const float* __restrict__ vproj, const int* __restrict__ sel_idx,
                 const int* __restrict__ sel_cnt, float* __restrict__ out)
{
    int q = blockIdx.x, h = blockIdx.y, tid = threadIdx.x;
    __shared__ __align__(16) float qv[192];
    __shared__ float logit[TOPK_K];
    __shared__ float red[4];
    __shared__ float ob[128];
    int cnt = sel_cnt[q];
    const int* sl = sel_idx + (long)q * TOPK_K;
    if (tid < 128)      qv[tid] = qp[((long)h * S_LEN + q) * IDIM + tid];
    else if (tid < 192) qv[tid] = qr[((long)h * S_LEN + q) * ROPE_D + (tid - 128)];
    __syncthreads();
    const float4* qv4 = (const float4*)qv;
    for (int i = tid; i < cnt; i += 256) {
        int k = sl[i];
        const float4* ke4 = (const float4*)(keff + ((long)k * NH + h) * IDIM);
        const float4* kr4 = (const float4*)(krot + (long)k * ROPE_D);
        float acc = 0.f;
        #pragma unroll 8
        for (int j = 0; j < 32; j++) {
            float4 a = qv4[j], bb = ke4[j];
            acc += a.x * bb.x + a.y * bb.y + a.z * bb.z + a.w * bb.w;
        }
        #pragma unroll 8
        for (int j = 0; j < 16; j++) {
            float4 a = qv4[32 + j], bb = kr4[j];
            acc += a.x * bb.x + a.y * bb.y + a.z * bb.z + a.w * bb.w;
        }
        logit[i] = acc * SCALING;
    }
    __syncthreads();
    float lmax = -1e30f;
    for (int i = tid; i < cnt; i += 256) lmax = fmaxf(lmax, logit[i]);
    for (int off = 32; off; off >>= 1) lmax = fmaxf(lmax, __shfl_down(lmax, off, 64));
    if ((tid & 63) == 0) red[tid >> 6] = lmax;
    __syncthreads();
    lmax = fmaxf(fmaxf(red[0], red[1]), fmaxf(red[2], red[3]));
    __syncthreads();
    float lsum = 0.f;
    for (int i = tid; i < cnt; i += 256) {
        float e = expf(logit[i] - lmax);
        logit[i] = e;
        lsum += e;
    }
    __syncthreads();
    for (int off = 32; off; off >>= 1) lsum += __shfl_down(lsum, off, 64);
    if ((tid & 63) == 0) red[tid >> 6] = lsum;
    __syncthreads();
    float inv = 1.f / (red[0] + red[1] + red[2] + red[3]);
    int d = tid & 127, part = tid >> 7;
    float o = 0.f;
    for (int i = part; i < cnt; i += 2) {
        int k = sl[i];
        o += logit[i] * vproj[((long)k * NH + h) * IDIM + d];
    }
    if (part == 0) ob[d] = o;
    __syncthreads();
    if (part == 1) out[((long)q * NH + h) * IDIM + d] = (ob[d] + o) * inv;
}

// ---------------------------------------------------------------------------
// Launch
// ---------------------------------------------------------------------------
extern "C" void kernel_launch(void* const* d_in, const int* in_sizes, int n_in,
                              void* d_out, int out_size, void* d_ws, size_t ws_size,
                              hipStream_t stream)
{
    const float* q_latent = (const float*)d_in[0];   // (2048,1536)
    const float* hidden   = (const float*)d_in[1];   // (2048,2048)
    const float* cosp     = (const float*)d_in[2];   // (2048,64)
    const float* sinp     = (const float*)d_in[3];   // (2048,64)
    const float* q_pass   = (const float*)d_in[4];   // (16,2048,128)
    const float* q_rot    = (const float*)d_in[5];   // (16,2048,64)
    const float* k_pass   = (const float*)d_in[6];   // (2048,512)
    const float* k_rot    = (const float*)d_in[7];   // (2048,64)
    // d_in[8] position_ids: unused by reference
    const float* kv_b     = (const float*)d_in[9];   // (4096,512)
    const float* wq_b_w   = (const float*)d_in[10];  // (2048,1536)
    const float* wk_w     = (const float*)d_in[11];  // (128,2048)
    const float* k_norm_w = (const float*)d_in[12];  // (64)
    const float* wproj_w  = (const float*)d_in[13];  // (16,2048)
    const float* wproj_b  = (const float*)d_in[14];  // (16)

    float* ws    = (float*)d_ws;
    float* ql    = ws;                                  // 2048*2048  -> index_q (in-place rope)
    float* ckv   = ql + 2048 * 2048;                    // 2048*128   -> index_k (in-place)
    float* wmat  = ckv + 2048 * 128;                    // 2048*16
    float* keff  = wmat + 2048 * 16;                    // 2048*16*128
    float* vproj = keff + 2048 * 16 * 128;              // 2048*16*128
    float* sc    = vproj + 2048 * 16 * 128;             // 2048*2048
    int* sel_idx = (int*)(sc + 2048 * 2048);            // 2048*1024
    int* sel_cnt = sel_idx + 2048 * 1024;               // 2048

    dim3 b256(256);
    // ql = q_latent @ wq_b_w^T
    gemm_abt<<<dim3(32, 32, 1), b256, 0, stream>>>(q_latent, wq_b_w, ql,
        2048, 2048, 1536, 1536, 1536, 2048, 0, 0, 0);
    // ckv = hidden @ wk_w^T
    gemm_abt<<<dim3(2, 32, 1), b256, 0, stream>>>(hidden, wk_w, ckv,
        2048, 128, 2048, 2048, 2048, 128, 0, 0, 0);
    // wmat = hidden @ wproj_w^T ; then |.+b|
    gemm_abt<<<dim3(1, 32, 1), b256, 0, stream>>>(hidden, wproj_w, wmat,
        2048, 16, 2048, 2048, 2048, 16, 0, 0, 0);
    absbias_inplace<<<dim3(128), b256, 0, stream>>>(wmat, wproj_b);
    // rope index_q (in-place on ql), build index_k (in-place on ckv)
    rope_iq_inplace<<<dim3(2048, 16), dim3(64), 0, stream>>>(ql, cosp, sinp);
    build_ik_inplace<<<dim3(2048), dim3(64), 0, stream>>>(ckv, cosp, sinp, k_norm_w);
    // k_eff[k,h,:] = k_b[h] @ k_pass[k]   (batched over h)
    gemm_abt<<<dim3(2, 32, 16), b256, 0, stream>>>(k_pass, kv_b, keff,
        2048, 128, 512, 512, 512, 2048, 0, 256 * 512, 128);
    // v_proj[k,h,:] = v_b[h] @ k_pass[k]
    gemm_abt<<<dim3(2, 32, 16), b256, 0, stream>>>(k_pass, kv_b + 128 * 512, vproj,
        2048, 128, 512, 512, 512, 2048, 0, 256 * 512, 128);
    // indexer scores (lower triangle only)
    scores_kernel<<<dim3(32, 32), b256, 0, stream>>>(ql, ckv, wmat, sc);
    // exact top-1024 per row
    topk_kernel<<<dim3(2048), b256, 0, stream>>>(sc, sel_idx, sel_cnt);
    // sparse attention + fused output projection
    attn_kernel<<<dim3(2048, 16), b256, 0, stream>>>(q_pass, q_rot, keff, k_rot,
        vproj, sel_idx, sel_cnt, (float*)d_out);
}

// Round 3
// 2404.322 us; speedup vs baseline: 2.1970x; 2.1970x over previous
//
#include <hip/hip_runtime.h>
#include <hip/hip_bf16.h>

// Problem constants (B=1)
#define S_LEN   2048
#define NH      16
#define ROPE_D  64
#define IDIM    128
#define KV_LORA 512
#define CDIM    576            // KV_LORA + ROPE_D (compressed attention dim)
#define TOPK_K  1024
#define SCALING 0.08838834764831845f   // 128^-0.5

typedef __attribute__((ext_vector_type(4))) float f32x4;
typedef __attribute__((ext_vector_type(8))) short s16x8;
typedef __attribute__((ext_vector_type(8))) unsigned short u16x8;

// ---------------------------------------------------------------------------
// Tiled GEMM: C = A @ B^T   (A: MxK, B: NxK row-major). Batched via grid.z.
// ---------------------------------------------------------------------------
#define BM 64
#define BN 64
#define BK 16

template<typename TA, typename TC>
__global__ __launch_bounds__(256)
void gemm_t(const TA* __restrict__ A, const float* __restrict__ B,
            TC* __restrict__ C,
            int M, int N, int K, int lda, int ldb, int ldc,
            long strideA, long strideB, long strideC)
{
    int bz = blockIdx.z;
    A += bz * strideA; B += bz * strideB; C += bz * strideC;
    __shared__ float As[BK][BM + 1];
    __shared__ float Bs[BK][BN + 1];
    int tid = threadIdx.x;
    int tx = tid & 15, ty = tid >> 4;
    int m0 = blockIdx.y * BM, n0 = blockIdx.x * BN;
    float acc[4][4] = {};
    for (int k0 = 0; k0 < K; k0 += BK) {
        for (int t = tid; t < BM * BK; t += 256) {
            int m = t >> 4, kk = t & 15;
            As[kk][m] = (m0 + m < M) ? (float)A[(long)(m0 + m) * lda + k0 + kk] : 0.f;
        }
        for (int t = tid; t < BN * BK; t += 256) {
            int nn = t >> 4, kk = t & 15;
            Bs[kk][nn] = (n0 + nn < N) ? B[(long)(n0 + nn) * ldb + k0 + kk] : 0.f;
        }
        __syncthreads();
        #pragma unroll
        for (int kk = 0; kk < BK; kk++) {
            float a[4], b[4];
            #pragma unroll
            for (int i = 0; i < 4; i++) a[i] = As[kk][ty * 4 + i];
            #pragma unroll
            for (int j = 0; j < 4; j++) b[j] = Bs[kk][tx * 4 + j];
            #pragma unroll
            for (int i = 0; i < 4; i++)
                #pragma unroll
                for (int j = 0; j < 4; j++) acc[i][j] += a[i] * b[j];
        }
        __syncthreads();
    }
    for (int i = 0; i < 4; i++) {
        int m = m0 + ty * 4 + i;
        if (m >= M) continue;
        for (int j = 0; j < 4; j++) {
            int n = n0 + tx * 4 + j;
            if (n < N) C[(long)m * ldc + n] = (TC)acc[i][j];
        }
    }
}

// ---------------------------------------------------------------------------
// Tiled GEMM: C = A @ B   (A: MxK, B: KxN row-major). Batched via grid.z.
// Used for q_abs = q_pass[h] @ k_b[h]  (k_b is K x N in memory: no transpose).
// ---------------------------------------------------------------------------
template<typename TA, typename TC>
__global__ __launch_bounds__(256)
void gemm_ab(const TA* __restrict__ A, const float* __restrict__ B,
             TC* __restrict__ C,
             int M, int N, int K, int lda, int ldb, int ldc,
             long strideA, long strideB, long strideC)
{
    int bz = blockIdx.z;
    A += bz * strideA; B += bz * strideB; C += bz * strideC;
    __shared__ float As[BK][BM + 1];
    __shared__ float Bs[BK][BN + 1];
    int tid = threadIdx.x;
    int tx = tid & 15, ty = tid >> 4;
    int m0 = blockIdx.y * BM, n0 = blockIdx.x * BN;
    float acc[4][4] = {};
    for (int k0 = 0; k0 < K; k0 += BK) {
        for (int t = tid; t < BM * BK; t += 256) {
            int m = t >> 4, kk = t & 15;
            As[kk][m] = (m0 + m < M) ? (float)A[(long)(m0 + m) * lda + k0 + kk] : 0.f;
        }
        for (int t = tid; t < BN * BK; t += 256) {
            int kk = t >> 6, nn = t & 63;        // coalesced along n
            Bs[kk][nn] = (n0 + nn < N) ? B[(long)(k0 + kk) * ldb + n0 + nn] : 0.f;
        }
        __syncthreads();
        #pragma unroll
        for (int kk = 0; kk < BK; kk++) {
            float a[4], b[4];
            #pragma unroll
            for (int i = 0; i < 4; i++) a[i] = As[kk][ty * 4 + i];
            #pragma unroll
            for (int j = 0; j < 4; j++) b[j] = Bs[kk][tx * 4 + j];
            #pragma unroll
            for (int i = 0; i < 4; i++)
                #pragma unroll
                for (int j = 0; j < 4; j++) acc[i][j] += a[i] * b[j];
        }
        __syncthreads();
    }
    for (int i = 0; i < 4; i++) {
        int m = m0 + ty * 4 + i;
        if (m >= M) continue;
        for (int j = 0; j < 4; j++) {
            int n = n0 + tx * 4 + j;
            if (n < N) C[(long)m * ldc + n] = (TC)acc[i][j];
        }
    }
}

// ---------------------------------------------------------------------------
// w = |gemm_out + bias|   (in-place), 2048*16 elements
// ---------------------------------------------------------------------------
__global__ void absbias_inplace(float* __restrict__ w, const float* __restrict__ b)
{
    int idx = blockIdx.x * 256 + threadIdx.x;
    if (idx < S_LEN * NH) w[idx] = fabsf(w[idx] + b[idx & 15]);
}

// ---------------------------------------------------------------------------
// In-place interleaved RoPE on ql rows -> index_q. One block (64 thr) per (s,h).
// ---------------------------------------------------------------------------
__global__ void rope_iq_inplace(float* __restrict__ ql,
                                const float* __restrict__ cosb,
                                const float* __restrict__ sinb)
{
    int s = blockIdx.x, h = blockIdx.y, i = threadIdx.x;   // i in [0,64)
    float* row = ql + (long)s * (NH * IDIM) + h * IDIM;
    float y  = (i < 32) ? row[2 * i]     : row[2 * (i - 32) + 1];
    float yr = (i < 32) ? -row[2 * i + 1] : row[2 * (i - 32)];
    float c  = cosb[s * ROPE_D + i];
    float sn = sinb[s * ROPE_D + i];
    float val = y * c + yr * sn;
    __syncthreads();
    row[i] = val;
}

// ---------------------------------------------------------------------------
// In-place build of index_k from ckv rows: rot half roped, pass half rmsnorm'd.
// ---------------------------------------------------------------------------
__global__ void build_ik_inplace(float* __restrict__ ckv,
                                 const float* __restrict__ cosb,
                                 const float* __restrict__ sinb,
                                 const float* __restrict__ knw)
{
    int k = blockIdx.x, i = threadIdx.x;   // i in [0,64)
    float* row = ckv + (long)k * IDIM;
    float y  = (i < 32) ? row[2 * i]     : row[2 * (i - 32) + 1];
    float yr = (i < 32) ? -row[2 * i + 1] : row[2 * (i - 32)];
    float c  = cosb[k * ROPE_D + i];
    float sn = sinb[k * ROPE_D + i];
    float rot = y * c + yr * sn;
    float xp = row[ROPE_D + i];
    float ss = xp * xp;
    for (int off = 32; off; off >>= 1) ss += __shfl_down(ss, off, 64);
    ss = __shfl(ss, 0, 64);
    float nv = xp * rsqrtf(ss / 64.f + 1e-6f) * knw[i];
    __syncthreads();
    row[i] = rot;
    row[ROPE_D + i] = nv;
}

// ---------------------------------------------------------------------------
// Indexer scores (fp32, exact selection path):
// sc[q][k] = sum_h w[q][h] * relu(SCALING * iq[q,h,:]·ik[k,:])
// ---------------------------------------------------------------------------
__global__ __launch_bounds__(256)
void scores_kernel(const float* __restrict__ iq, const float* __restrict__ ik,
                   const float* __restrict__ w, float* __restrict__ sc)
{
    int bk = blockIdx.x, bq = blockIdx.y;
    if (bk > bq) return;
    int q0 = bq * 64, k0 = bk * 64;
    __shared__ float Qs[64][33];
    __shared__ float Ks[64][33];
    __shared__ float Ws[64][17];
    int tid = threadIdx.x;
    int tx = tid & 15, ty = tid >> 4;
    for (int i = tid; i < 64 * 16; i += 256)
        Ws[i >> 4][i & 15] = w[(q0 + (i >> 4)) * NH + (i & 15)];
    float fin[4][4] = {};
    for (int h = 0; h < NH; h++) {
        float acc[4][4] = {};
        for (int dc = 0; dc < 4; dc++) {
            __syncthreads();
            for (int i = tid; i < 64 * 32; i += 256) {
                int r = i >> 5, d = i & 31;
                Qs[r][d] = iq[((long)(q0 + r) * NH + h) * IDIM + dc * 32 + d];
                Ks[r][d] = ik[(long)(k0 + r) * IDIM + dc * 32 + d];
            }
            __syncthreads();
            #pragma unroll
            for (int kk = 0; kk < 32; kk++) {
                float a[4], b[4];
                #pragma unroll
                for (int i = 0; i < 4; i++) a[i] = Qs[ty * 4 + i][kk];
                #pragma unroll
                for (int j = 0; j < 4; j++) b[j] = Ks[tx * 4 + j][kk];
                #pragma unroll
                for (int i = 0; i < 4; i++)
                    #pragma unroll
                    for (int j = 0; j < 4; j++) acc[i][j] += a[i] * b[j];
            }
        }
        #pragma unroll
        for (int i = 0; i < 4; i++)
            #pragma unroll
            for (int j = 0; j < 4; j++) {
                float v = acc[i][j] * SCALING;
                v = v > 0.f ? v : 0.f;
                fin[i][j] += v * Ws[ty * 4 + i][h];
            }
    }
    for (int i = 0; i < 4; i++)
        for (int j = 0; j < 4; j++)
            sc[(long)(q0 + ty * 4 + i) * S_LEN + k0 + tx * 4 + j] = fin[i][j];
}

// ---------------------------------------------------------------------------
// Exact top-1024 per row via radix-select on float bits (scores >= 0).
// ---------------------------------------------------------------------------
__device__ __forceinline__ int block_scan_excl(int v, volatile int* lds, int tid, int* total)
{
    lds[tid] = v;
    __syncthreads();
    int x = v;
    for (int off = 1; off < 256; off <<= 1) {
        int y = (tid >= off) ? lds[tid - off] : 0;
        __syncthreads();
        x += y;
        lds[tid] = x;
        __syncthreads();
    }
    int t = lds[255];
    __syncthreads();
    *total = t;
    return x - v;
}

__global__ __launch_bounds__(256)
void topk_kernel(const float* __restrict__ sc, int* __restrict__ sel_idx)
{
    __shared__ int lds[256];
    __shared__ int wsum[4];
    int q = blockIdx.x, tid = threadIdx.x;
    int n = q + 1;
    int* row_sel = sel_idx + (long)q * TOPK_K;
    if (n <= TOPK_K) {
        for (int i = tid; i < n; i += 256) row_sel[i] = i;
        return;
    }
    const float* row = sc + (long)q * S_LEN;
    unsigned bits[8];
    int base = tid * 8;
    #pragma unroll
    for (int i = 0; i < 8; i++) {
        int k = base + i;
        bits[i] = (k < n) ? __float_as_uint(row[k]) : 0u;
    }
    unsigned prefix = 0;
    for (int bit = 30; bit >= 0; bit--) {
        unsigned cand = prefix | (1u << bit);
        int c = 0;
        #pragma unroll
        for (int i = 0; i < 8; i++) c += (bits[i] >= cand) ? 1 : 0;
        for (int off = 32; off; off >>= 1) c += __shfl_down(c, off, 64);
        if ((tid & 63) == 0) wsum[tid >> 6] = c;
        __syncthreads();
        int total = wsum[0] + wsum[1] + wsum[2] + wsum[3];
        __syncthreads();
        if (total >= TOPK_K) prefix = cand;
    }
    unsigned v = prefix;
    int lgt = 0, leq = 0;
    #pragma unroll
    for (int i = 0; i < 8; i++) {
        int k = base + i;
        if (k >= n) break;
        if (bits[i] > v) lgt++;
        else if (bits[i] == v) leq++;
    }
    int tot_gt, tot_eq;
    int gt_off = block_scan_excl(lgt, lds, tid, &tot_gt);
    int eq_off = block_scan_excl(leq, lds, tid, &tot_eq);
    int fill = TOPK_K - tot_gt;
    int gpos = gt_off, epos = eq_off;
    for (int i = 0; i < 8; i++) {
        int k = base + i;
        if (k >= n) break;
        if (bits[i] > v) {
            row_sel[gpos++] = k;
        } else if (bits[i] == v) {
            if (epos < fill) row_sel[tot_gt + epos] = k;
            epos++;
        }
    }
}

// ---------------------------------------------------------------------------
// Pack kernels (fp32 -> bf16)
// ---------------------------------------------------------------------------
__global__ void pack_kv(const float* __restrict__ k_pass, const float* __restrict__ k_rot,
                        __hip_bfloat16* __restrict__ kvb)
{
    int k = blockIdx.x;
    for (int i = threadIdx.x; i < CDIM; i += 256) {
        float v = (i < KV_LORA) ? k_pass[(long)k * KV_LORA + i]
                                : k_rot[(long)k * ROPE_D + (i - KV_LORA)];
        kvb[(long)k * CDIM + i] = __float2bfloat16(v);
    }
}

__global__ void pack_qrot(const float* __restrict__ q_rot, __hip_bfloat16* __restrict__ Qcat)
{
    int q = blockIdx.x;
    for (int j = threadIdx.x; j < NH * ROPE_D; j += 256) {
        int h = j >> 6, i = j & 63;
        Qcat[((long)q * NH + h) * CDIM + KV_LORA + i] =
            __float2bfloat16(q_rot[((long)h * S_LEN + q) * ROPE_D + i]);
    }
}

// ---------------------------------------------------------------------------
// MLA compressed-space sparse attention. One block (4 waves) per q.
//  S^T(32k x 16h) = KVtile . Q^T   (bf16 MFMA, A-frags gathered from global)
//  online softmax per head; PV: O_c(16h x 512) += P . Kpass_tile (MFMA),
//  Kpass tile staged transposed in LDS as packed key-pair u32 words.
// ---------------------------------------------------------------------------
__global__ __launch_bounds__(256)
void attn_mla(const __hip_bfloat16* __restrict__ Qcat,   // [q][h][576]
              const __hip_bfloat16* __restrict__ kvb,    // [k][576]
              const int* __restrict__ sel_idx,
              __hip_bfloat16* __restrict__ Oc,           // [qloc][h][512]
              int qbase)
{
    __shared__ __align__(16) unsigned short Qs[16][584];   // 18,688 B
    __shared__ __align__(16) unsigned int   KT[512][20];   // 40,960 B (dim x keypair)
    __shared__ float Spart[4][16][17];                     //  4,352 B
    __shared__ __align__(16) unsigned short Pb[16][40];    //  1,280 B
    __shared__ float mst[16], lst[16], alph[16];           //    192 B  (total 65,472)

    const int q   = blockIdx.x + qbase;
    const int tid = threadIdx.x;
    const int wv  = tid >> 6;
    const int ln  = tid & 63;
    const int g   = ln >> 4;          // 0..3
    const int lo  = ln & 15;
    const int cnt = (q + 1 < TOPK_K) ? (q + 1) : TOPK_K;
    const int* sel = sel_idx + (long)q * TOPK_K;
    const unsigned short* kvu = (const unsigned short*)kvb;

    // Stage Q block: 16 heads x 576 bf16
    {
        const unsigned short* qrow = (const unsigned short*)(Qcat + (long)q * NH * CDIM);
        for (int i = tid; i < 16 * 72; i += 256) {
            int h = i / 72, c8 = i % 72;
            *(u16x8*)&Qs[h][c8 * 8] = *(const u16x8*)&qrow[h * CDIM + c8 * 8];
        }
        if (tid < 16) { mst[tid] = -1e30f; lst[tid] = 0.f; }
    }
    f32x4 O[8];
    #pragma unroll
    for (int s = 0; s < 8; s++) O[s] = (f32x4){0.f, 0.f, 0.f, 0.f};

    const int mt = wv >> 1;           // key M-tile (0..1)
    const int kp = wv & 1;            // K-part (0..1), 9 chunks of 32 dims each
    const int ntiles = (cnt + 31) >> 5;

    for (int t = 0; t < ntiles; t++) {
        __syncthreads();   // prev tile's PV done with KT/Pb; Qs ready (t=0)

        // --- S^T partial: keys t*32 + mt*16 + lo, dims [kp*288, kp*288+288)
        int kidx = t * 32 + mt * 16 + lo;
        int krow = sel[kidx < cnt ? kidx : cnt - 1];
        const unsigned short* kvr = kvu + (long)krow * CDIM + g * 8;
        f32x4 acc = {0.f, 0.f, 0.f, 0.f};
        #pragma unroll
        for (int c = 0; c < 9; c++) {
            int cc = kp * 9 + c;
            s16x8 a = *(const s16x8*)(kvr + cc * 32);
            s16x8 b = *(const s16x8*)&Qs[lo][cc * 32 + g * 8];
            acc = __builtin_amdgcn_mfma_f32_16x16x32_bf16(a, b, acc, 0, 0, 0);
        }
        #pragma unroll
        for (int r = 0; r < 4; r++) Spart[wv][g * 4 + r][lo] = acc[r];

        // --- transpose-gather Kpass tile into KT[dim][keypair]
        #pragma unroll
        for (int u = 0; u < 4; u++) {
            int uid = u * 256 + tid;
            int tkp = uid & 15, c = uid >> 4;   // c in 0..63 (8-dim chunks)
            int k0 = t * 32 + tkp * 2, k1 = k0 + 1;
            int r0 = sel[k0 < cnt ? k0 : cnt - 1];
            int r1 = sel[k1 < cnt ? k1 : cnt - 1];
            u16x8 a0 = *(const u16x8*)(kvu + (long)r0 * CDIM + c * 8);
            u16x8 a1 = *(const u16x8*)(kvu + (long)r1 * CDIM + c * 8);
            #pragma unroll
            for (int d = 0; d < 8; d++)
                KT[c * 8 + d][tkp] = (unsigned)a0[d] | ((unsigned)a1[d] << 16);
        }
        __syncthreads();   // KT + Spart visible

        // --- softmax update (wave 0 only)
        if (wv == 0) {
            float p[8];
            float mx = -1e30f;
            #pragma unroll
            for (int j = 0; j < 8; j++) {
                int kloc = g * 8 + j;
                float s = (Spart[(kloc >> 4) * 2][kloc & 15][lo] +
                           Spart[(kloc >> 4) * 2 + 1][kloc & 15][lo]) * SCALING;
                if (t * 32 + kloc >= cnt) s = -1e30f;
                p[j] = s;
                mx = fmaxf(mx, s);
            }
            mx = fmaxf(mx, __shfl_xor(mx, 16, 64));
            mx = fmaxf(mx, __shfl_xor(mx, 32, 64));
            float mo = mst[lo];
            float mn = fmaxf(mo, mx);
            float al = __expf(mo - mn);
            float sum = 0.f;
            #pragma unroll
            for (int j = 0; j < 8; j++) {
                float e = __expf(p[j] - mn);
                p[j] = e; sum += e;
            }
            sum += __shfl_xor(sum, 16, 64);
            sum += __shfl_xor(sum, 32, 64);
            if (g == 0) { mst[lo] = mn; lst[lo] = lst[lo] * al + sum; alph[lo] = al; }
            u16x8 pw;
            #pragma unroll
            for (int j = 0; j < 8; j++) {
                __hip_bfloat16 hb = __float2bfloat16(p[j]);
                pw[j] = *(unsigned short*)&hb;
            }
            *(u16x8*)&Pb[lo][g * 8] = pw;
        }
        __syncthreads();   // Pb + alph visible

        // --- rescale O, then PV MFMA over this tile's 32 keys
        float al4[4];
        #pragma unroll
        for (int r = 0; r < 4; r++) al4[r] = alph[g * 4 + r];
        #pragma unroll
        for (int s = 0; s < 8; s++)
            #pragma unroll
            for (int r = 0; r < 4; r++) O[s][r] *= al4[r];
        s16x8 pa = *(const s16x8*)&Pb[lo][g * 8];
        #pragma unroll
        for (int s = 0; s < 8; s++) {
            s16x8 bkt = *(const s16x8*)&KT[wv * 128 + s * 16 + lo][g * 4];
            O[s] = __builtin_amdgcn_mfma_f32_16x16x32_bf16(pa, bkt, O[s], 0, 0, 0);
        }
    }
    __syncthreads();
    float linv[4];
    #pragma unroll
    for (int r = 0; r < 4; r++) linv[r] = 1.f / lst[g * 4 + r];
    #pragma unroll
    for (int s = 0; s < 8; s++) {
        int dim = wv * 128 + s * 16 + lo;
        #pragma unroll
        for (int r = 0; r < 4; r++) {
            int h = g * 4 + r;
            Oc[((long)blockIdx.x * NH + h) * KV_LORA + dim] = __float2bfloat16(O[s][r] * linv[r]);
        }
    }
}

// ---------------------------------------------------------------------------
// Launch
// ---------------------------------------------------------------------------
extern "C" void kernel_launch(void* const* d_in, const int* in_sizes, int n_in,
                              void* d_out, int out_size, void* d_ws, size_t ws_size,
                              hipStream_t stream)
{
    const float* q_latent = (const float*)d_in[0];   // (2048,1536)
    const float* hidden   = (const float*)d_in[1];   // (2048,2048)
    const float* cosp     = (const float*)d_in[2];   // (2048,64)
    const float* sinp     = (const float*)d_in[3];   // (2048,64)
    const float* q_pass   = (const float*)d_in[4];   // (16,2048,128)
    const float* q_rot    = (const float*)d_in[5];   // (16,2048,64)
    const float* k_pass   = (const float*)d_in[6];   // (2048,512)
    const float* k_rot    = (const float*)d_in[7];   // (2048,64)
    const float* kv_b     = (const float*)d_in[9];   // (4096,512)
    const float* wq_b_w   = (const float*)d_in[10];  // (2048,1536)
    const float* wk_w     = (const float*)d_in[11];  // (128,2048)
    const float* k_norm_w = (const float*)d_in[12];  // (64)
    const float* wproj_w  = (const float*)d_in[13];  // (16,2048)
    const float* wproj_b  = (const float*)d_in[14];  // (16)

    float* ws = (float*)d_ws;
    // sel_idx lives first (persistent across both phases).
    int* sel_idx = (int*)ws;                             // 2,097,152 ints
    // Phase 1 (indexer fp32):
    float* ql   = ws + 2097152;                          // 4,194,304 f
    float* ckv  = ws + 6291456;                          //   262,144 f
    float* wmat = ws + 6553600;                          //    32,768 f
    float* sc   = ws + 6586368;                          // 4,194,304 f (ends 10,780,672)
    // Phase 2 (attention bf16) — aliases phase-1 region (strictly after topk):
    __hip_bfloat16* Qcat = (__hip_bfloat16*)(ws + 2097152);   // 18,874,368 bf16 (ends f-off 11,534,336)
    __hip_bfloat16* kvb  = (__hip_bfloat16*)(ws + 11534336);  //  1,179,648 bf16 (ends 12,124,160)
    __hip_bfloat16* Oc   = (__hip_bfloat16*)(ws + 12124160);  //  8,388,608 bf16 = half of q (ends 16,318,464 f = 65.3 MB)

    dim3 b256(256);
    // --- indexer path (fp32, exact selection) ---
    gemm_t<float, float><<<dim3(32, 32, 1), b256, 0, stream>>>(q_latent, wq_b_w, ql,
        2048, 2048, 1536, 1536, 1536, 2048, 0, 0, 0);
    gemm_t<float, float><<<dim3(2, 32, 1), b256, 0, stream>>>(hidden, wk_w, ckv,
        2048, 128, 2048, 2048, 2048, 128, 0, 0, 0);
    gemm_t<float, float><<<dim3(1, 32, 1), b256, 0, stream>>>(hidden, wproj_w, wmat,
        2048, 16, 2048, 2048, 2048, 16, 0, 0, 0);
    absbias_inplace<<<dim3(128), b256, 0, stream>>>(wmat, wproj_b);
    rope_iq_inplace<<<dim3(2048, 16), dim3(64), 0, stream>>>(ql, cosp, sinp);
    build_ik_inplace<<<dim3(2048), dim3(64), 0, stream>>>(ckv, cosp, sinp, k_norm_w);
    scores_kernel<<<dim3(32, 32), b256, 0, stream>>>(ql, ckv, wmat, sc);
    topk_kernel<<<dim3(2048), b256, 0, stream>>>(sc, sel_idx);

    // --- attention path (bf16 MFMA, compressed space) ---
    // q_abs[h] = q_pass[h] (2048x128) @ k_b[h] (128x512, row-major K x N) -> Qcat[:, h, 0:512]
    gemm_ab<float, __hip_bfloat16><<<dim3(8, 32, 16), b256, 0, stream>>>(
        q_pass, kv_b, Qcat, 2048, 512, 128,
        128, 512, NH * CDIM, 2048L * 128, 256L * 512, CDIM);
    pack_qrot<<<dim3(2048), b256, 0, stream>>>(q_rot, Qcat);
    pack_kv<<<dim3(2048), b256, 0, stream>>>(k_pass, k_rot, kvb);

    // Two q-halves to halve the Oc footprint (ws safety).
    for (int half = 0; half < 2; half++) {
        int qb = half * 1024;
        attn_mla<<<dim3(1024), b256, 0, stream>>>(Qcat, kvb, sel_idx, Oc, qb);
        // out[q][h][d] = O_c[q][h][:] . v_b[h][d][:]   (v_b rows are N x K: A@B^T)
        gemm_t<__hip_bfloat16, float><<<dim3(2, 16, 16), b256, 0, stream>>>(
            Oc, kv_b + 128 * 512, (float*)d_out + (long)qb * NH * IDIM,
            1024, 128, 512,
            512 * NH, 512, 128 * NH, 512L, 256L * 512, 128L);
    }
}

// Round 5
// 1745.004 us; speedup vs baseline: 3.0271x; 1.3778x over previous
//
#include <hip/hip_runtime.h>
#include <hip/hip_bf16.h>

// Problem constants (B=1)
#define S_LEN   2048
#define NH      16
#define ROPE_D  64
#define IDIM    128
#define KV_LORA 512
#define CDIM    576            // KV_LORA + ROPE_D (compressed attention dim)
#define TOPK_K  1024
#define SCALING 0.08838834764831845f   // 128^-0.5

typedef __attribute__((ext_vector_type(4))) float f32x4;
typedef __attribute__((ext_vector_type(8))) short s16x8;
typedef __attribute__((ext_vector_type(8))) unsigned short u16x8;

static __device__ __forceinline__ unsigned short bf16_bits(float v)
{
    __hip_bfloat16 h = __float2bfloat16(v);
    return *(unsigned short*)&h;
}

// ---------------------------------------------------------------------------
// fp32 tiled GEMM: C = A @ B^T (kept for the small ckv / wmat GEMMs)
// ---------------------------------------------------------------------------
#define BM 64
#define BN 64
#define BK 16

__global__ __launch_bounds__(256)
void gemm_t(const float* __restrict__ A, const float* __restrict__ B,
            float* __restrict__ C,
            int M, int N, int K, int lda, int ldb, int ldc)
{
    __shared__ float As[BK][BM + 1];
    __shared__ float Bs[BK][BN + 1];
    int tid = threadIdx.x;
    int tx = tid & 15, ty = tid >> 4;
    int m0 = blockIdx.y * BM, n0 = blockIdx.x * BN;
    float acc[4][4] = {};
    for (int k0 = 0; k0 < K; k0 += BK) {
        for (int t = tid; t < BM * BK; t += 256) {
            int m = t >> 4, kk = t & 15;
            As[kk][m] = (m0 + m < M) ? A[(long)(m0 + m) * lda + k0 + kk] : 0.f;
        }
        for (int t = tid; t < BN * BK; t += 256) {
            int nn = t >> 4, kk = t & 15;
            Bs[kk][nn] = (n0 + nn < N) ? B[(long)(n0 + nn) * ldb + k0 + kk] : 0.f;
        }
        __syncthreads();
        #pragma unroll
        for (int kk = 0; kk < BK; kk++) {
            float a[4], b[4];
            #pragma unroll
            for (int i = 0; i < 4; i++) a[i] = As[kk][ty * 4 + i];
            #pragma unroll
            for (int j = 0; j < 4; j++) b[j] = Bs[kk][tx * 4 + j];
            #pragma unroll
            for (int i = 0; i < 4; i++)
                #pragma unroll
                for (int j = 0; j < 4; j++) acc[i][j] += a[i] * b[j];
        }
        __syncthreads();
    }
    for (int i = 0; i < 4; i++) {
        int m = m0 + ty * 4 + i;
        if (m >= M) continue;
        for (int j = 0; j < 4; j++) {
            int n = n0 + tx * 4 + j;
            if (n < N) C[(long)m * ldc + n] = acc[i][j];
        }
    }
}

// ---------------------------------------------------------------------------
// Elementwise packs
// ---------------------------------------------------------------------------
__global__ void pack_split(const float* __restrict__ x, unsigned short* __restrict__ hi,
                           unsigned short* __restrict__ lo, long n)
{
    long i = (long)blockIdx.x * 256 + threadIdx.x;
    if (i < n) {
        float v = x[i];
        __hip_bfloat16 h = __float2bfloat16(v);
        float hv = __bfloat162float(h);
        hi[i] = *(unsigned short*)&h;
        lo[i] = bf16_bits(v - hv);
    }
}

__global__ void pack_bf16(const float* __restrict__ x, unsigned short* __restrict__ y, long n)
{
    long i = (long)blockIdx.x * 256 + threadIdx.x;
    if (i < n) y[i] = bf16_bits(x[i]);
}

// kbT[h][n(512)][k(128)] = kv_b[(h*256 + k)*512 + n]  (transposed k_b, bf16)
__global__ void pack_kbT(const float* __restrict__ kv_b, unsigned short* __restrict__ kbT)
{
    long i = (long)blockIdx.x * 256 + threadIdx.x;   // 16*512*128
    int k = i & 127, n = (i >> 7) & 511, h = i >> 16;
    kbT[i] = bf16_bits(kv_b[((long)h * 256 + k) * 512 + n]);
}

// vb[h][d(128)][r(512)] = kv_b[(h*256+128+d)*512 + r]  (v_b, bf16)
__global__ void pack_vb(const float* __restrict__ kv_b, unsigned short* __restrict__ vb)
{
    long i = (long)blockIdx.x * 256 + threadIdx.x;   // 16*128*512
    int r = i & 511, d = (i >> 9) & 127, h = i >> 16;
    vb[i] = bf16_bits(kv_b[((long)h * 256 + 128 + d) * 512 + r]);
}

// ---------------------------------------------------------------------------
// w = |gemm_out + bias|, in-place
// ---------------------------------------------------------------------------
__global__ void absbias_inplace(float* __restrict__ w, const float* __restrict__ b)
{
    int idx = blockIdx.x * 256 + threadIdx.x;
    if (idx < S_LEN * NH) w[idx] = fabsf(w[idx] + b[idx & 15]);
}

// ---------------------------------------------------------------------------
// In-place interleaved RoPE on ql -> index_q
// ---------------------------------------------------------------------------
__global__ void rope_iq_inplace(float* __restrict__ ql,
                                const float* __restrict__ cosb,
                                const float* __restrict__ sinb)
{
    int s = blockIdx.x, h = blockIdx.y, i = threadIdx.x;   // i in [0,64)
    float* row = ql + (long)s * (NH * IDIM) + h * IDIM;
    float y  = (i < 32) ? row[2 * i]     : row[2 * (i - 32) + 1];
    float yr = (i < 32) ? -row[2 * i + 1] : row[2 * (i - 32)];
    float c  = cosb[s * ROPE_D + i];
    float sn = sinb[s * ROPE_D + i];
    float val = y * c + yr * sn;
    __syncthreads();
    row[i] = val;
}

// ---------------------------------------------------------------------------
// In-place build of index_k from ckv rows
// ---------------------------------------------------------------------------
__global__ void build_ik_inplace(float* __restrict__ ckv,
                                 const float* __restrict__ cosb,
                                 const float* __restrict__ sinb,
                                 const float* __restrict__ knw)
{
    int k = blockIdx.x, i = threadIdx.x;   // i in [0,64)
    float* row = ckv + (long)k * IDIM;
    float y  = (i < 32) ? row[2 * i]     : row[2 * (i - 32) + 1];
    float yr = (i < 32) ? -row[2 * i + 1] : row[2 * (i - 32)];
    float c  = cosb[k * ROPE_D + i];
    float sn = sinb[k * ROPE_D + i];
    float rot = y * c + yr * sn;
    float xp = row[ROPE_D + i];
    float ss = xp * xp;
    for (int off = 32; off; off >>= 1) ss += __shfl_down(ss, off, 64);
    ss = __shfl(ss, 0, 64);
    float nv = xp * rsqrtf(ss / 64.f + 1e-6f) * knw[i];
    __syncthreads();
    row[i] = rot;
    row[ROPE_D + i] = nv;
}

// ---------------------------------------------------------------------------
// Split-bf16 MFMA GEMM: C(fp32) = A @ B^T, A,B given as (hi,lo) bf16 pairs.
// hi*hi + hi*lo + lo*hi ~= fp32 product. No LDS; frags streamed from global.
// ---------------------------------------------------------------------------
__global__ __launch_bounds__(256)
void gemm_split3(const unsigned short* __restrict__ Ah, const unsigned short* __restrict__ Al,
                 const unsigned short* __restrict__ Bh, const unsigned short* __restrict__ Bl,
                 float* __restrict__ C, int N, int K, int lda, int ldb, int ldc)
{
    int tid = threadIdx.x, wv = tid >> 6, ln = tid & 63, g = ln >> 4, lo = ln & 15;
    int m0 = blockIdx.y * 64 + wv * 16, n0 = blockIdx.x * 64;
    f32x4 acc[4] = {};
    for (int kc = 0; kc < K; kc += 32) {
        long aoff = (long)(m0 + lo) * lda + kc + g * 8;
        s16x8 ah = *(const s16x8*)&Ah[aoff];
        s16x8 al = *(const s16x8*)&Al[aoff];
        #pragma unroll
        for (int nt = 0; nt < 4; nt++) {
            long boff = (long)(n0 + nt * 16 + lo) * ldb + kc + g * 8;
            s16x8 bh = *(const s16x8*)&Bh[boff];
            s16x8 bl = *(const s16x8*)&Bl[boff];
            acc[nt] = __builtin_amdgcn_mfma_f32_16x16x32_bf16(ah, bh, acc[nt], 0, 0, 0);
            acc[nt] = __builtin_amdgcn_mfma_f32_16x16x32_bf16(ah, bl, acc[nt], 0, 0, 0);
            acc[nt] = __builtin_amdgcn_mfma_f32_16x16x32_bf16(al, bh, acc[nt], 0, 0, 0);
        }
    }
    #pragma unroll
    for (int nt = 0; nt < 4; nt++)
        #pragma unroll
        for (int r = 0; r < 4; r++)
            C[(long)(m0 + g * 4 + r) * ldc + n0 + nt * 16 + lo] = acc[nt][r];
}

// ---------------------------------------------------------------------------
// Plain bf16 MFMA GEMM: C = A @ B^T (A: MxK bf16, B: NxK bf16). Batched grid.z.
// No LDS. K passed EXPLICITLY (lda may exceed K for strided row layouts).
// ---------------------------------------------------------------------------
template<typename TC>
__global__ __launch_bounds__(256)
void gemm_bf16(const unsigned short* __restrict__ A, const unsigned short* __restrict__ B,
               TC* __restrict__ C, int K, int lda, int ldb, int ldc,
               long sA, long sB, long sC)
{
    A += (long)blockIdx.z * sA; B += (long)blockIdx.z * sB; C += (long)blockIdx.z * sC;
    int tid = threadIdx.x, wv = tid >> 6, ln = tid & 63, g = ln >> 4, lo = ln & 15;
    int m0 = blockIdx.y * 64 + wv * 16, n0 = blockIdx.x * 64;
    f32x4 acc[4] = {};
    for (int kc = 0; kc < K; kc += 32) {
        s16x8 a = *(const s16x8*)&A[(long)(m0 + lo) * lda + kc + g * 8];
        #pragma unroll
        for (int nt = 0; nt < 4; nt++) {
            s16x8 b = *(const s16x8*)&B[(long)(n0 + nt * 16 + lo) * ldb + kc + g * 8];
            acc[nt] = __builtin_amdgcn_mfma_f32_16x16x32_bf16(a, b, acc[nt], 0, 0, 0);
        }
    }
    #pragma unroll
    for (int nt = 0; nt < 4; nt++)
        #pragma unroll
        for (int r = 0; r < 4; r++)
            C[(long)(m0 + g * 4 + r) * ldc + n0 + nt * 16 + lo] = (TC)acc[nt][r];
}

// ---------------------------------------------------------------------------
// Indexer scores via split-bf16 MFMA.
// sc[q][k] = sum_h w[q][h] * relu(SCALING * iq[q,h,:].ik[k,:])
// ---------------------------------------------------------------------------
__global__ __launch_bounds__(256)
void scores_mfma(const unsigned short* __restrict__ iq_hi, const unsigned short* __restrict__ iq_lo,
                 const unsigned short* __restrict__ ik_hi, const unsigned short* __restrict__ ik_lo,
                 const float* __restrict__ w, float* __restrict__ sc)
{
    int bk = blockIdx.x, bq = blockIdx.y;
    if (bk > bq) return;
    int q0 = bq * 64, k0 = bk * 64;
    __shared__ __align__(16) unsigned short Khi[64][136];
    __shared__ __align__(16) unsigned short Klo[64][136];
    __shared__ float Ws[64][17];
    int tid = threadIdx.x, wv = tid >> 6, ln = tid & 63, g = ln >> 4, lo = ln & 15;

    for (int i = tid; i < 64 * 16; i += 256) {
        int r = i >> 4, c8 = i & 15;
        *(u16x8*)&Khi[r][c8 * 8] = *(const u16x8*)&ik_hi[(long)(k0 + r) * IDIM + c8 * 8];
        *(u16x8*)&Klo[r][c8 * 8] = *(const u16x8*)&ik_lo[(long)(k0 + r) * IDIM + c8 * 8];
    }
    for (int i = tid; i < 64 * 16; i += 256)
        Ws[i >> 4][i & 15] = w[(long)(q0 + (i >> 4)) * NH + (i & 15)];
    __syncthreads();

    float fin[4][4][4] = {};   // [mt][nt][r]
    #pragma unroll
    for (int hh = 0; hh < 4; hh++) {
        int h = wv * 4 + hh;
        #pragma unroll
        for (int mg = 0; mg < 2; mg++) {
            f32x4 acc[2][4] = {};
            #pragma unroll
            for (int kc = 0; kc < 4; kc++) {
                s16x8 ah[2], al[2];
                #pragma unroll
                for (int mi = 0; mi < 2; mi++) {
                    long off = ((long)(q0 + (mg * 2 + mi) * 16 + lo) * NH + h) * IDIM + kc * 32 + g * 8;
                    ah[mi] = *(const s16x8*)&iq_hi[off];
                    al[mi] = *(const s16x8*)&iq_lo[off];
                }
                #pragma unroll
                for (int nt = 0; nt < 4; nt++) {
                    s16x8 bh = *(const s16x8*)&Khi[nt * 16 + lo][kc * 32 + g * 8];
                    s16x8 bl = *(const s16x8*)&Klo[nt * 16 + lo][kc * 32 + g * 8];
                    #pragma unroll
                    for (int mi = 0; mi < 2; mi++) {
                        acc[mi][nt] = __builtin_amdgcn_mfma_f32_16x16x32_bf16(ah[mi], bh, acc[mi][nt], 0, 0, 0);
                        acc[mi][nt] = __builtin_amdgcn_mfma_f32_16x16x32_bf16(ah[mi], bl, acc[mi][nt], 0, 0, 0);
                        acc[mi][nt] = __builtin_amdgcn_mfma_f32_16x16x32_bf16(al[mi], bh, acc[mi][nt], 0, 0, 0);
                    }
                }
            }
            #pragma unroll
            for (int mi = 0; mi < 2; mi++) {
                int mt = mg * 2 + mi;
                #pragma unroll
                for (int r = 0; r < 4; r++) {
                    float wqh = Ws[mt * 16 + g * 4 + r][h];
                    #pragma unroll
                    for (int nt = 0; nt < 4; nt++) {
                        float v = acc[mi][nt][r] * SCALING;
                        v = v > 0.f ? v : 0.f;
                        fin[mt][nt][r] += v * wqh;
                    }
                }
            }
        }
    }
    // cross-wave reduction of fin (reuse Khi storage)
    __syncthreads();
    float (*FinBuf)[68] = (float(*)[68])&Khi[0][0];   // 64x68 floats = 17,408 B
    for (int wt = 0; wt < 4; wt++) {
        if (wv == wt) {
            #pragma unroll
            for (int mt = 0; mt < 4; mt++)
                #pragma unroll
                for (int r = 0; r < 4; r++)
                    #pragma unroll
                    for (int nt = 0; nt < 4; nt++) {
                        if (wt == 0) FinBuf[mt * 16 + g * 4 + r][nt * 16 + lo] = fin[mt][nt][r];
                        else         FinBuf[mt * 16 + g * 4 + r][nt * 16 + lo] += fin[mt][nt][r];
                    }
        }
        __syncthreads();
    }
    for (int i = tid; i < 64 * 16; i += 256) {
        int r = i >> 4, c4 = i & 15;
        *(f32x4*)&sc[(long)(q0 + r) * S_LEN + k0 + c4 * 4] = *(f32x4*)&FinBuf[r][c4 * 4];
    }
}

// ---------------------------------------------------------------------------
// Exact top-1024 per row via radix-select on float bits (scores >= 0).
// ---------------------------------------------------------------------------
__device__ __forceinline__ int block_scan_excl(int v, volatile int* lds, int tid, int* total)
{
    lds[tid] = v;
    __syncthreads();
    int x = v;
    for (int off = 1; off < 256; off <<= 1) {
        int y = (tid >= off) ? lds[tid - off] : 0;
        __syncthreads();
        x += y;
        lds[tid] = x;
        __syncthreads();
    }
    int t = lds[255];
    __syncthreads();
    *total = t;
    return x - v;
}

__global__ __launch_bounds__(256)
void topk_kernel(const float* __restrict__ sc, int* __restrict__ sel_idx)
{
    __shared__ int lds[256];
    __shared__ int wsum[4];
    int q = blockIdx.x, tid = threadIdx.x;
    int n = q + 1;
    int* row_sel = sel_idx + (long)q * TOPK_K;
    if (n <= TOPK_K) {
        for (int i = tid; i < n; i += 256) row_sel[i] = i;
        return;
    }
    const float* row = sc + (long)q * S_LEN;
    unsigned bits[8];
    int base = tid * 8;
    #pragma unroll
    for (int i = 0; i < 8; i++) {
        int k = base + i;
        bits[i] = (k < n) ? __float_as_uint(row[k]) : 0u;
    }
    unsigned prefix = 0;
    for (int bit = 30; bit >= 0; bit--) {
        unsigned cand = prefix | (1u << bit);
        int c = 0;
        #pragma unroll
        for (int i = 0; i < 8; i++) c += (bits[i] >= cand) ? 1 : 0;
        for (int off = 32; off; off >>= 1) c += __shfl_down(c, off, 64);
        if ((tid & 63) == 0) wsum[tid >> 6] = c;
        __syncthreads();
        int total = wsum[0] + wsum[1] + wsum[2] + wsum[3];
        __syncthreads();
        if (total >= TOPK_K) prefix = cand;
    }
    unsigned v = prefix;
    int lgt = 0, leq = 0;
    #pragma unroll
    for (int i = 0; i < 8; i++) {
        int k = base + i;
        if (k >= n) break;
        if (bits[i] > v) lgt++;
        else if (bits[i] == v) leq++;
    }
    int tot_gt, tot_eq;
    int gt_off = block_scan_excl(lgt, lds, tid, &tot_gt);
    int eq_off = block_scan_excl(leq, lds, tid, &tot_eq);
    int fill = TOPK_K - tot_gt;
    int gpos = gt_off, epos = eq_off;
    for (int i = 0; i < 8; i++) {
        int k = base + i;
        if (k >= n) break;
        if (bits[i] > v) {
            row_sel[gpos++] = k;
        } else if (bits[i] == v) {
            if (epos < fill) row_sel[tot_gt + epos] = k;
            epos++;
        }
    }
}

// ---------------------------------------------------------------------------
// bf16 packs for the attention path
// ---------------------------------------------------------------------------
__global__ void pack_kv(const float* __restrict__ k_pass, const float* __restrict__ k_rot,
                        __hip_bfloat16* __restrict__ kvb)
{
    int k = blockIdx.x;
    for (int i = threadIdx.x; i < CDIM; i += 256) {
        float v = (i < KV_LORA) ? k_pass[(long)k * KV_LORA + i]
                                : k_rot[(long)k * ROPE_D + (i - KV_LORA)];
        kvb[(long)k * CDIM + i] = __float2bfloat16(v);
    }
}

__global__ void pack_qrot(const float* __restrict__ q_rot, __hip_bfloat16* __restrict__ Qcat)
{
    int q = blockIdx.x;
    for (int j = threadIdx.x; j < NH * ROPE_D; j += 256) {
        int h = j >> 6, i = j & 63;
        Qcat[((long)q * NH + h) * CDIM + KV_LORA + i] =
            __float2bfloat16(q_rot[((long)h * S_LEN + q) * ROPE_D + i]);
    }
}

// ---------------------------------------------------------------------------
// MLA compressed-space sparse attention. One block (4 waves) per q.
// Q B-frags streamed from global (18 KB/block, L1/L2-resident); LDS 38.6 KB
// -> 4 blocks/CU.
// ---------------------------------------------------------------------------
__global__ __launch_bounds__(256)
void attn_mla(const __hip_bfloat16* __restrict__ Qcat,   // [q][h][576]
              const __hip_bfloat16* __restrict__ kvb,    // [k][576]
              const int* __restrict__ sel_idx,
              __hip_bfloat16* __restrict__ Oc,           // [qloc][h][512]
              int qbase)
{
    __shared__ __align__(16) unsigned int   KT[512][16];   // 32,768 B (dim x keypair)
    __shared__ float Spart[4][16][17];                     //  4,352 B
    __shared__ __align__(16) unsigned short Pb[16][40];    //  1,280 B
    __shared__ float mst[16], lst[16], alph[16];           //    192 B

    const int q   = blockIdx.x + qbase;
    const int tid = threadIdx.x;
    const int wv  = tid >> 6;
    const int ln  = tid & 63;
    const int g   = ln >> 4;          // 0..3
    const int lo  = ln & 15;
    const int cnt = (q + 1 < TOPK_K) ? (q + 1) : TOPK_K;
    const int* sel = sel_idx + (long)q * TOPK_K;
    const unsigned short* kvu = (const unsigned short*)kvb;
    const unsigned short* qrow = (const unsigned short*)(Qcat + (long)q * NH * CDIM);

    if (tid < 16) { mst[tid] = -1e30f; lst[tid] = 0.f; }

    f32x4 O[8];
    #pragma unroll
    for (int s = 0; s < 8; s++) O[s] = (f32x4){0.f, 0.f, 0.f, 0.f};

    const int mt = wv >> 1;           // key M-tile (0..1)
    const int kp = wv & 1;            // K-part (0..1), 9 chunks of 32 dims each
    const int ntiles = (cnt + 31) >> 5;

    for (int t = 0; t < ntiles; t++) {
        __syncthreads();   // prev tile's PV done with KT/Pb; mst/lst init (t=0)

        // --- S^T partial: keys t*32 + mt*16 + lo, dims [kp*288, kp*288+288)
        int kidx = t * 32 + mt * 16 + lo;
        int krow = sel[kidx < cnt ? kidx : cnt - 1];
        const unsigned short* kvr = kvu + (long)krow * CDIM + g * 8;
        f32x4 acc = {0.f, 0.f, 0.f, 0.f};
        #pragma unroll
        for (int c = 0; c < 9; c++) {
            int cc = kp * 9 + c;
            s16x8 a = *(const s16x8*)(kvr + cc * 32);
            s16x8 b = *(const s16x8*)&qrow[lo * CDIM + cc * 32 + g * 8];
            acc = __builtin_amdgcn_mfma_f32_16x16x32_bf16(a, b, acc, 0, 0, 0);
        }
        #pragma unroll
        for (int r = 0; r < 4; r++) Spart[wv][g * 4 + r][lo] = acc[r];

        // --- transpose-gather Kpass tile into KT[dim][keypair]
        #pragma unroll
        for (int u = 0; u < 4; u++) {
            int uid = u * 256 + tid;
            int tkp = uid & 15, c = uid >> 4;   // c in 0..63 (8-dim chunks)
            int k0 = t * 32 + tkp * 2, k1 = k0 + 1;
            int r0 = sel[k0 < cnt ? k0 : cnt - 1];
            int r1 = sel[k1 < cnt ? k1 : cnt - 1];
            u16x8 a0 = *(const u16x8*)(kvu + (long)r0 * CDIM + c * 8);
            u16x8 a1 = *(const u16x8*)(kvu + (long)r1 * CDIM + c * 8);
            #pragma unroll
            for (int d = 0; d < 8; d++)
                KT[c * 8 + d][tkp] = (unsigned)a0[d] | ((unsigned)a1[d] << 16);
        }
        __syncthreads();   // KT + Spart visible

        // --- softmax update (wave 0 only)
        if (wv == 0) {
            float p[8];
            float mx = -1e30f;
            #pragma unroll
            for (int j = 0; j < 8; j++) {
                int kloc = g * 8 + j;
                float s = (Spart[(kloc >> 4) * 2][kloc & 15][lo] +
                           Spart[(kloc >> 4) * 2 + 1][kloc & 15][lo]) * SCALING;
                if (t * 32 + kloc >= cnt) s = -1e30f;
                p[j] = s;
                mx = fmaxf(mx, s);
            }
            mx = fmaxf(mx, __shfl_xor(mx, 16, 64));
            mx = fmaxf(mx, __shfl_xor(mx, 32, 64));
            float mo = mst[lo];
            float mn = fmaxf(mo, mx);
            float al = __expf(mo - mn);
            float sum = 0.f;
            #pragma unroll
            for (int j = 0; j < 8; j++) {
                float e = __expf(p[j] - mn);
                p[j] = e; sum += e;
            }
            sum += __shfl_xor(sum, 16, 64);
            sum += __shfl_xor(sum, 32, 64);
            if (g == 0) { mst[lo] = mn; lst[lo] = lst[lo] * al + sum; alph[lo] = al; }
            u16x8 pw;
            #pragma unroll
            for (int j = 0; j < 8; j++) pw[j] = bf16_bits(p[j]);
            *(u16x8*)&Pb[lo][g * 8] = pw;
        }
        __syncthreads();   // Pb + alph visible

        // --- rescale O, then PV MFMA over this tile's 32 keys
        float al4[4];
        #pragma unroll
        for (int r = 0; r < 4; r++) al4[r] = alph[g * 4 + r];
        #pragma unroll
        for (int s = 0; s < 8; s++)
            #pragma unroll
            for (int r = 0; r < 4; r++) O[s][r] *= al4[r];
        s16x8 pa = *(const s16x8*)&Pb[lo][g * 8];
        #pragma unroll
        for (int s = 0; s < 8; s++) {
            s16x8 bkt = *(const s16x8*)&KT[wv * 128 + s * 16 + lo][g * 4];
            O[s] = __builtin_amdgcn_mfma_f32_16x16x32_bf16(pa, bkt, O[s], 0, 0, 0);
        }
    }
    __syncthreads();
    float linv[4];
    #pragma unroll
    for (int r = 0; r < 4; r++) linv[r] = 1.f / lst[g * 4 + r];
    #pragma unroll
    for (int s = 0; s < 8; s++) {
        int dim = wv * 128 + s * 16 + lo;
        #pragma unroll
        for (int r = 0; r < 4; r++) {
            int h = g * 4 + r;
            Oc[((long)blockIdx.x * NH + h) * KV_LORA + dim] = __float2bfloat16(O[s][r] * linv[r]);
        }
    }
}

// ---------------------------------------------------------------------------
// Launch
// ---------------------------------------------------------------------------
extern "C" void kernel_launch(void* const* d_in, const int* in_sizes, int n_in,
                              void* d_out, int out_size, void* d_ws, size_t ws_size,
                              hipStream_t stream)
{
    const float* q_latent = (const float*)d_in[0];   // (2048,1536)
    const float* hidden   = (const float*)d_in[1];   // (2048,2048)
    const float* cosp     = (const float*)d_in[2];   // (2048,64)
    const float* sinp     = (const float*)d_in[3];   // (2048,64)
    const float* q_pass   = (const float*)d_in[4];   // (16,2048,128)
    const float* q_rot    = (const float*)d_in[5];   // (16,2048,64)
    const float* k_pass   = (const float*)d_in[6];   // (2048,512)
    const float* k_rot    = (const float*)d_in[7];   // (2048,64)
    const float* kv_b     = (const float*)d_in[9];   // (4096,512)
    const float* wq_b_w   = (const float*)d_in[10];  // (2048,1536)
    const float* wk_w     = (const float*)d_in[11];  // (128,2048)
    const float* k_norm_w = (const float*)d_in[12];  // (64)
    const float* wproj_w  = (const float*)d_in[13];  // (16,2048)
    const float* wproj_b  = (const float*)d_in[14];  // (16)

    float* ws = (float*)d_ws;
    // Persistent: sel_idx
    int* sel_idx = (int*)ws;                                       // [0 .. 2,097,152)
    // Phase 1a: split inputs for ql GEMM
    unsigned short* qlat_hi = (unsigned short*)(ws + 2097152);
    unsigned short* qlat_lo = (unsigned short*)(ws + 3670016);
    unsigned short* wq_hi   = (unsigned short*)(ws + 5242880);
    unsigned short* wq_lo   = (unsigned short*)(ws + 6815744);     // ends 8,388,608 f
    float* ql = ws + 8388608;                                      // 4,194,304 f -> 12,582,912
    // Phase 1b (after ql GEMM; aliases qlat/wq region):
    unsigned short* iq_hi = (unsigned short*)(ws + 2097152);
    unsigned short* iq_lo = (unsigned short*)(ws + 4194304);
    unsigned short* ik_hi = (unsigned short*)(ws + 6291456);
    unsigned short* ik_lo = (unsigned short*)(ws + 6422528);
    float* wmat = ws + 6553600;                                    // 32,768 f
    float* ckv  = ws + 6586368;                                    // 262,144 f -> 6,848,512
    float* sc   = ws + 8388608;                                    // aliases ql (dead after pack iq)
    // Phase 2 (after topk; aliases phase-1):
    __hip_bfloat16* Qcat = (__hip_bfloat16*)(ws + 2097152);        // ends f-off 11,534,336
    __hip_bfloat16* kvb  = (__hip_bfloat16*)(ws + 11534336);       // -> 12,124,160
    unsigned short* kbT  = (unsigned short*)(ws + 12124160);       // -> 12,648,448
    unsigned short* vb   = (unsigned short*)(ws + 12648448);       // -> 13,172,736
    unsigned short* qp   = (unsigned short*)(ws + 13172736);       // -> 15,269,888
    __hip_bfloat16* Oc   = (__hip_bfloat16*)(ws + 13172736);       // aliases qp; -> 17,367,040 f (69.5 MB)

    dim3 b256(256);
    // --- indexer path (split-bf16 MFMA, selection-exact) ---
    pack_split<<<dim3(12288), b256, 0, stream>>>(q_latent, qlat_hi, qlat_lo, 2048L * 1536);
    pack_split<<<dim3(12288), b256, 0, stream>>>(wq_b_w, wq_hi, wq_lo, 2048L * 1536);
    gemm_split3<<<dim3(32, 32), b256, 0, stream>>>(qlat_hi, qlat_lo, wq_hi, wq_lo,
        ql, 2048, 1536, 1536, 1536, 2048);
    rope_iq_inplace<<<dim3(2048, 16), dim3(64), 0, stream>>>(ql, cosp, sinp);
    pack_split<<<dim3(16384), b256, 0, stream>>>(ql, iq_hi, iq_lo, 2048L * 2048);
    gemm_t<<<dim3(2, 32), b256, 0, stream>>>(hidden, wk_w, ckv,
        2048, 128, 2048, 2048, 2048, 128);
    build_ik_inplace<<<dim3(2048), dim3(64), 0, stream>>>(ckv, cosp, sinp, k_norm_w);
    pack_split<<<dim3(1024), b256, 0, stream>>>(ckv, ik_hi, ik_lo, 2048L * 128);
    gemm_t<<<dim3(1, 32), b256, 0, stream>>>(hidden, wproj_w, wmat,
        2048, 16, 2048, 2048, 2048, 16);
    absbias_inplace<<<dim3(128), b256, 0, stream>>>(wmat, wproj_b);
    scores_mfma<<<dim3(32, 32), b256, 0, stream>>>(iq_hi, iq_lo, ik_hi, ik_lo, wmat, sc);
    topk_kernel<<<dim3(2048), b256, 0, stream>>>(sc, sel_idx);

    // --- attention path (bf16 MFMA, compressed space) ---
    pack_bf16<<<dim3(16384), b256, 0, stream>>>(q_pass, qp, 16L * 2048 * 128);
    pack_kbT<<<dim3(4096), b256, 0, stream>>>(kv_b, kbT);
    pack_vb<<<dim3(4096), b256, 0, stream>>>(kv_b, vb);
    pack_kv<<<dim3(2048), b256, 0, stream>>>(k_pass, k_rot, kvb);
    // q_abs[h] = qp[h] (2048x128) @ kbT[h]^T (512x128): K=128
    gemm_bf16<__hip_bfloat16><<<dim3(8, 32, 16), b256, 0, stream>>>(
        qp, kbT, (__hip_bfloat16*)Qcat, 128, 128, 128, NH * CDIM,
        2048L * 128, 512L * 128, (long)CDIM);
    pack_qrot<<<dim3(2048), b256, 0, stream>>>(q_rot, Qcat);

    // Two q-halves to bound the Oc footprint.
    for (int half = 0; half < 2; half++) {
        int qb = half * 1024;
        attn_mla<<<dim3(1024), b256, 0, stream>>>(Qcat, kvb, sel_idx, Oc, qb);
        // out[q][h][d] = Oc[q][h][:512] . vb[h][d][:512]: K=512 (lda=8192!)
        gemm_bf16<float><<<dim3(2, 16, 16), b256, 0, stream>>>(
            (const unsigned short*)Oc, vb, (float*)d_out + (long)qb * NH * IDIM,
            512, NH * KV_LORA, KV_LORA, NH * IDIM,
            512L, 128L * 512, (long)IDIM);
    }
}

// Round 6
// 1287.858 us; speedup vs baseline: 4.1016x; 1.3550x over previous
//
#include <hip/hip_runtime.h>
#include <hip/hip_bf16.h>

// Problem constants (B=1)
#define S_LEN   2048
#define NH      16
#define ROPE_D  64
#define IDIM    128
#define KV_LORA 512
#define CDIM    576            // KV_LORA + ROPE_D (compressed attention dim)
#define TOPK_K  1024
#define SCALING 0.08838834764831845f   // 128^-0.5

typedef __attribute__((ext_vector_type(4))) float f32x4;
typedef __attribute__((ext_vector_type(8))) short s16x8;
typedef __attribute__((ext_vector_type(8))) unsigned short u16x8;
typedef __attribute__((ext_vector_type(2))) unsigned int uint2v;

static __device__ __forceinline__ unsigned short bf16_bits(float v)
{
    __hip_bfloat16 h = __float2bfloat16(v);
    return *(unsigned short*)&h;
}

#define BM 64
#define BN 64
#define BK 16

// ---------------------------------------------------------------------------
// Fused split-K projection: part[ks][m][n] = hidden[m, ks*256:+256] @ W^T
// where W rows = [wk_w(128 rows); wproj_w(16 rows)], N=144 total.
// grid (3 n-tiles, 32 m-tiles, 8 k-splits) = 768 blocks.
// ---------------------------------------------------------------------------
#define PKC 256

__global__ __launch_bounds__(256)
void proj_splitk(const float* __restrict__ hidden, const float* __restrict__ wk_w,
                 const float* __restrict__ wproj_w, float* __restrict__ part)
{
    int nt = blockIdx.x, mt = blockIdx.y, ks = blockIdx.z;
    int n0 = nt * 64, m0 = mt * 64, k00 = ks * PKC;
    __shared__ float As[BK][BM + 1];
    __shared__ float Bs[BK][BN + 1];
    int tid = threadIdx.x, tx = tid & 15, ty = tid >> 4;
    float acc[4][4] = {};
    for (int k0 = 0; k0 < PKC; k0 += BK) {
        for (int t = tid; t < BM * BK; t += 256) {
            int m = t >> 4, kk = t & 15;
            As[kk][m] = hidden[(long)(m0 + m) * 2048 + k00 + k0 + kk];
        }
        for (int t = tid; t < BN * BK; t += 256) {
            int nn = t >> 4, kk = t & 15;
            int n = n0 + nn;
            float v = 0.f;
            if (n < 128)      v = wk_w[(long)n * 2048 + k00 + k0 + kk];
            else if (n < 144) v = wproj_w[(long)(n - 128) * 2048 + k00 + k0 + kk];
            Bs[kk][nn] = v;
        }
        __syncthreads();
        #pragma unroll
        for (int kk = 0; kk < BK; kk++) {
            float a[4], b[4];
            #pragma unroll
            for (int i = 0; i < 4; i++) a[i] = As[kk][ty * 4 + i];
            #pragma unroll
            for (int j = 0; j < 4; j++) b[j] = Bs[kk][tx * 4 + j];
            #pragma unroll
            for (int i = 0; i < 4; i++)
                #pragma unroll
                for (int j = 0; j < 4; j++) acc[i][j] += a[i] * b[j];
        }
        __syncthreads();
    }
    for (int i = 0; i < 4; i++) {
        int m = m0 + ty * 4 + i;
        for (int j = 0; j < 4; j++) {
            int n = n0 + tx * 4 + j;
            if (n < 144) part[((long)ks * S_LEN + m) * 144 + n] = acc[i][j];
        }
    }
}

__global__ void proj_reduce(const float* __restrict__ part, float* __restrict__ ckv,
                            float* __restrict__ wmat)
{
    int i = blockIdx.x * 256 + threadIdx.x;
    if (i >= S_LEN * 144) return;
    int m = i / 144, n = i % 144;
    float s = 0.f;
    #pragma unroll
    for (int ks = 0; ks < 8; ks++) s += part[((long)ks * S_LEN + m) * 144 + n];
    if (n < 128) ckv[(long)m * 128 + n] = s;
    else         wmat[(long)m * 16 + (n - 128)] = s;
}

// ---------------------------------------------------------------------------
// Elementwise packs
// ---------------------------------------------------------------------------
__global__ void pack_split(const float* __restrict__ x, unsigned short* __restrict__ hi,
                           unsigned short* __restrict__ lo, long n)
{
    long i = (long)blockIdx.x * 256 + threadIdx.x;
    if (i < n) {
        float v = x[i];
        __hip_bfloat16 h = __float2bfloat16(v);
        float hv = __bfloat162float(h);
        hi[i] = *(unsigned short*)&h;
        lo[i] = bf16_bits(v - hv);
    }
}

__global__ void pack_bf16(const float* __restrict__ x, unsigned short* __restrict__ y, long n)
{
    long i = (long)blockIdx.x * 256 + threadIdx.x;
    if (i < n) y[i] = bf16_bits(x[i]);
}

// kbT[h][n(512)][k(128)] = kv_b[(h*256 + k)*512 + n]
__global__ void pack_kbT(const float* __restrict__ kv_b, unsigned short* __restrict__ kbT)
{
    long i = (long)blockIdx.x * 256 + threadIdx.x;
    int k = i & 127, n = (i >> 7) & 511, h = i >> 16;
    kbT[i] = bf16_bits(kv_b[((long)h * 256 + k) * 512 + n]);
}

// vb[h][d(128)][r(512)] = kv_b[(h*256+128+d)*512 + r]
__global__ void pack_vb(const float* __restrict__ kv_b, unsigned short* __restrict__ vb)
{
    long i = (long)blockIdx.x * 256 + threadIdx.x;
    int r = i & 511, d = (i >> 9) & 127, h = i >> 16;
    vb[i] = bf16_bits(kv_b[((long)h * 256 + 128 + d) * 512 + r]);
}

// ---------------------------------------------------------------------------
// w = |gemm_out + bias|, in-place
// ---------------------------------------------------------------------------
__global__ void absbias_inplace(float* __restrict__ w, const float* __restrict__ b)
{
    int idx = blockIdx.x * 256 + threadIdx.x;
    if (idx < S_LEN * NH) w[idx] = fabsf(w[idx] + b[idx & 15]);
}

// ---------------------------------------------------------------------------
// In-place interleaved RoPE on ql -> index_q
// ---------------------------------------------------------------------------
__global__ void rope_iq_inplace(float* __restrict__ ql,
                                const float* __restrict__ cosb,
                                const float* __restrict__ sinb)
{
    int s = blockIdx.x, h = blockIdx.y, i = threadIdx.x;   // i in [0,64)
    float* row = ql + (long)s * (NH * IDIM) + h * IDIM;
    float y  = (i < 32) ? row[2 * i]     : row[2 * (i - 32) + 1];
    float yr = (i < 32) ? -row[2 * i + 1] : row[2 * (i - 32)];
    float c  = cosb[s * ROPE_D + i];
    float sn = sinb[s * ROPE_D + i];
    float val = y * c + yr * sn;
    __syncthreads();
    row[i] = val;
}

// ---------------------------------------------------------------------------
// In-place build of index_k from ckv rows
// ---------------------------------------------------------------------------
__global__ void build_ik_inplace(float* __restrict__ ckv,
                                 const float* __restrict__ cosb,
                                 const float* __restrict__ sinb,
                                 const float* __restrict__ knw)
{
    int k = blockIdx.x, i = threadIdx.x;   // i in [0,64)
    float* row = ckv + (long)k * IDIM;
    float y  = (i < 32) ? row[2 * i]     : row[2 * (i - 32) + 1];
    float yr = (i < 32) ? -row[2 * i + 1] : row[2 * (i - 32)];
    float c  = cosb[k * ROPE_D + i];
    float sn = sinb[k * ROPE_D + i];
    float rot = y * c + yr * sn;
    float xp = row[ROPE_D + i];
    float ss = xp * xp;
    for (int off = 32; off; off >>= 1) ss += __shfl_down(ss, off, 64);
    ss = __shfl(ss, 0, 64);
    float nv = xp * rsqrtf(ss / 64.f + 1e-6f) * knw[i];
    __syncthreads();
    row[i] = rot;
    row[ROPE_D + i] = nv;
}

// ---------------------------------------------------------------------------
// Split-bf16 MFMA GEMM: C(fp32) = A @ B^T, A,B given as (hi,lo) bf16 pairs.
// ---------------------------------------------------------------------------
__global__ __launch_bounds__(256)
void gemm_split3(const unsigned short* __restrict__ Ah, const unsigned short* __restrict__ Al,
                 const unsigned short* __restrict__ Bh, const unsigned short* __restrict__ Bl,
                 float* __restrict__ C, int N, int K, int lda, int ldb, int ldc)
{
    int tid = threadIdx.x, wv = tid >> 6, ln = tid & 63, g = ln >> 4, lo = ln & 15;
    int m0 = blockIdx.y * 64 + wv * 16, n0 = blockIdx.x * 64;
    f32x4 acc[4] = {};
    for (int kc = 0; kc < K; kc += 32) {
        long aoff = (long)(m0 + lo) * lda + kc + g * 8;
        s16x8 ah = *(const s16x8*)&Ah[aoff];
        s16x8 al = *(const s16x8*)&Al[aoff];
        #pragma unroll
        for (int nt = 0; nt < 4; nt++) {
            long boff = (long)(n0 + nt * 16 + lo) * ldb + kc + g * 8;
            s16x8 bh = *(const s16x8*)&Bh[boff];
            s16x8 bl = *(const s16x8*)&Bl[boff];
            acc[nt] = __builtin_amdgcn_mfma_f32_16x16x32_bf16(ah, bh, acc[nt], 0, 0, 0);
            acc[nt] = __builtin_amdgcn_mfma_f32_16x16x32_bf16(ah, bl, acc[nt], 0, 0, 0);
            acc[nt] = __builtin_amdgcn_mfma_f32_16x16x32_bf16(al, bh, acc[nt], 0, 0, 0);
        }
    }
    #pragma unroll
    for (int nt = 0; nt < 4; nt++)
        #pragma unroll
        for (int r = 0; r < 4; r++)
            C[(long)(m0 + g * 4 + r) * ldc + n0 + nt * 16 + lo] = acc[nt][r];
}

// ---------------------------------------------------------------------------
// Plain bf16 MFMA GEMM: C = A @ B^T. K explicit (lda may exceed K).
// ---------------------------------------------------------------------------
template<typename TC>
__global__ __launch_bounds__(256)
void gemm_bf16(const unsigned short* __restrict__ A, const unsigned short* __restrict__ B,
               TC* __restrict__ C, int K, int lda, int ldb, int ldc,
               long sA, long sB, long sC)
{
    A += (long)blockIdx.z * sA; B += (long)blockIdx.z * sB; C += (long)blockIdx.z * sC;
    int tid = threadIdx.x, wv = tid >> 6, ln = tid & 63, g = ln >> 4, lo = ln & 15;
    int m0 = blockIdx.y * 64 + wv * 16, n0 = blockIdx.x * 64;
    f32x4 acc[4] = {};
    for (int kc = 0; kc < K; kc += 32) {
        s16x8 a = *(const s16x8*)&A[(long)(m0 + lo) * lda + kc + g * 8];
        #pragma unroll
        for (int nt = 0; nt < 4; nt++) {
            s16x8 b = *(const s16x8*)&B[(long)(n0 + nt * 16 + lo) * ldb + kc + g * 8];
            acc[nt] = __builtin_amdgcn_mfma_f32_16x16x32_bf16(a, b, acc[nt], 0, 0, 0);
        }
    }
    #pragma unroll
    for (int nt = 0; nt < 4; nt++)
        #pragma unroll
        for (int r = 0; r < 4; r++)
            C[(long)(m0 + g * 4 + r) * ldc + n0 + nt * 16 + lo] = (TC)acc[nt][r];
}

// ---------------------------------------------------------------------------
// Indexer scores via split-bf16 MFMA.
// ---------------------------------------------------------------------------
__global__ __launch_bounds__(256)
void scores_mfma(const unsigned short* __restrict__ iq_hi, const unsigned short* __restrict__ iq_lo,
                 const unsigned short* __restrict__ ik_hi, const unsigned short* __restrict__ ik_lo,
                 const float* __restrict__ w, float* __restrict__ sc)
{
    int bk = blockIdx.x, bq = blockIdx.y;
    if (bk > bq) return;
    int q0 = bq * 64, k0 = bk * 64;
    __shared__ __align__(16) unsigned short Khi[64][136];
    __shared__ __align__(16) unsigned short Klo[64][136];
    __shared__ float Ws[64][17];
    int tid = threadIdx.x, wv = tid >> 6, ln = tid & 63, g = ln >> 4, lo = ln & 15;

    for (int i = tid; i < 64 * 16; i += 256) {
        int r = i >> 4, c8 = i & 15;
        *(u16x8*)&Khi[r][c8 * 8] = *(const u16x8*)&ik_hi[(long)(k0 + r) * IDIM + c8 * 8];
        *(u16x8*)&Klo[r][c8 * 8] = *(const u16x8*)&ik_lo[(long)(k0 + r) * IDIM + c8 * 8];
    }
    for (int i = tid; i < 64 * 16; i += 256)
        Ws[i >> 4][i & 15] = w[(long)(q0 + (i >> 4)) * NH + (i & 15)];
    __syncthreads();

    float fin[4][4][4] = {};   // [mt][nt][r]
    #pragma unroll
    for (int hh = 0; hh < 4; hh++) {
        int h = wv * 4 + hh;
        #pragma unroll
        for (int mg = 0; mg < 2; mg++) {
            f32x4 acc[2][4] = {};
            #pragma unroll
            for (int kc = 0; kc < 4; kc++) {
                s16x8 ah[2], al[2];
                #pragma unroll
                for (int mi = 0; mi < 2; mi++) {
                    long off = ((long)(q0 + (mg * 2 + mi) * 16 + lo) * NH + h) * IDIM + kc * 32 + g * 8;
                    ah[mi] = *(const s16x8*)&iq_hi[off];
                    al[mi] = *(const s16x8*)&iq_lo[off];
                }
                #pragma unroll
                for (int nt = 0; nt < 4; nt++) {
                    s16x8 bh = *(const s16x8*)&Khi[nt * 16 + lo][kc * 32 + g * 8];
                    s16x8 bl = *(const s16x8*)&Klo[nt * 16 + lo][kc * 32 + g * 8];
                    #pragma unroll
                    for (int mi = 0; mi < 2; mi++) {
                        acc[mi][nt] = __builtin_amdgcn_mfma_f32_16x16x32_bf16(ah[mi], bh, acc[mi][nt], 0, 0, 0);
                        acc[mi][nt] = __builtin_amdgcn_mfma_f32_16x16x32_bf16(ah[mi], bl, acc[mi][nt], 0, 0, 0);
                        acc[mi][nt] = __builtin_amdgcn_mfma_f32_16x16x32_bf16(al[mi], bh, acc[mi][nt], 0, 0, 0);
                    }
                }
            }
            #pragma unroll
            for (int mi = 0; mi < 2; mi++) {
                int mt = mg * 2 + mi;
                #pragma unroll
                for (int r = 0; r < 4; r++) {
                    float wqh = Ws[mt * 16 + g * 4 + r][h];
                    #pragma unroll
                    for (int nt = 0; nt < 4; nt++) {
                        float v = acc[mi][nt][r] * SCALING;
                        v = v > 0.f ? v : 0.f;
                        fin[mt][nt][r] += v * wqh;
                    }
                }
            }
        }
    }
    __syncthreads();
    float (*FinBuf)[68] = (float(*)[68])&Khi[0][0];
    for (int wt = 0; wt < 4; wt++) {
        if (wv == wt) {
            #pragma unroll
            for (int mt = 0; mt < 4; mt++)
                #pragma unroll
                for (int r = 0; r < 4; r++)
                    #pragma unroll
                    for (int nt = 0; nt < 4; nt++) {
                        if (wt == 0) FinBuf[mt * 16 + g * 4 + r][nt * 16 + lo] = fin[mt][nt][r];
                        else         FinBuf[mt * 16 + g * 4 + r][nt * 16 + lo] += fin[mt][nt][r];
                    }
        }
        __syncthreads();
    }
    for (int i = tid; i < 64 * 16; i += 256) {
        int r = i >> 4, c4 = i & 15;
        *(f32x4*)&sc[(long)(q0 + r) * S_LEN + k0 + c4 * 4] = *(f32x4*)&FinBuf[r][c4 * 4];
    }
}

// ---------------------------------------------------------------------------
// Exact top-1024 per row via radix-select on float bits (scores >= 0).
// ---------------------------------------------------------------------------
__device__ __forceinline__ int block_scan_excl(int v, volatile int* lds, int tid, int* total)
{
    lds[tid] = v;
    __syncthreads();
    int x = v;
    for (int off = 1; off < 256; off <<= 1) {
        int y = (tid >= off) ? lds[tid - off] : 0;
        __syncthreads();
        x += y;
        lds[tid] = x;
        __syncthreads();
    }
    int t = lds[255];
    __syncthreads();
    *total = t;
    return x - v;
}

__global__ __launch_bounds__(256)
void topk_kernel(const float* __restrict__ sc, int* __restrict__ sel_idx)
{
    __shared__ int lds[256];
    __shared__ int wsum[4];
    int q = blockIdx.x, tid = threadIdx.x;
    int n = q + 1;
    int* row_sel = sel_idx + (long)q * TOPK_K;
    if (n <= TOPK_K) {
        for (int i = tid; i < n; i += 256) row_sel[i] = i;
        return;
    }
    const float* row = sc + (long)q * S_LEN;
    unsigned bits[8];
    int base = tid * 8;
    #pragma unroll
    for (int i = 0; i < 8; i++) {
        int k = base + i;
        bits[i] = (k < n) ? __float_as_uint(row[k]) : 0u;
    }
    unsigned prefix = 0;
    for (int bit = 30; bit >= 0; bit--) {
        unsigned cand = prefix | (1u << bit);
        int c = 0;
        #pragma unroll
        for (int i = 0; i < 8; i++) c += (bits[i] >= cand) ? 1 : 0;
        for (int off = 32; off; off >>= 1) c += __shfl_down(c, off, 64);
        if ((tid & 63) == 0) wsum[tid >> 6] = c;
        __syncthreads();
        int total = wsum[0] + wsum[1] + wsum[2] + wsum[3];
        __syncthreads();
        if (total >= TOPK_K) prefix = cand;
    }
    unsigned v = prefix;
    int lgt = 0, leq = 0;
    #pragma unroll
    for (int i = 0; i < 8; i++) {
        int k = base + i;
        if (k >= n) break;
        if (bits[i] > v) lgt++;
        else if (bits[i] == v) leq++;
    }
    int tot_gt, tot_eq;
    int gt_off = block_scan_excl(lgt, lds, tid, &tot_gt);
    int eq_off = block_scan_excl(leq, lds, tid, &tot_eq);
    int fill = TOPK_K - tot_gt;
    int gpos = gt_off, epos = eq_off;
    for (int i = 0; i < 8; i++) {
        int k = base + i;
        if (k >= n) break;
        if (bits[i] > v) {
            row_sel[gpos++] = k;
        } else if (bits[i] == v) {
            if (epos < fill) row_sel[tot_gt + epos] = k;
            epos++;
        }
    }
}

// ---------------------------------------------------------------------------
// bf16 packs for the attention path
// ---------------------------------------------------------------------------
__global__ void pack_kv(const float* __restrict__ k_pass, const float* __restrict__ k_rot,
                        __hip_bfloat16* __restrict__ kvb)
{
    int k = blockIdx.x;
    for (int i = threadIdx.x; i < CDIM; i += 256) {
        float v = (i < KV_LORA) ? k_pass[(long)k * KV_LORA + i]
                                : k_rot[(long)k * ROPE_D + (i - KV_LORA)];
        kvb[(long)k * CDIM + i] = __float2bfloat16(v);
    }
}

__global__ void pack_qrot(const float* __restrict__ q_rot, __hip_bfloat16* __restrict__ Qcat)
{
    int q = blockIdx.x;
    for (int j = threadIdx.x; j < NH * ROPE_D; j += 256) {
        int h = j >> 6, i = j & 63;
        Qcat[((long)q * NH + h) * CDIM + KV_LORA + i] =
            __float2bfloat16(q_rot[((long)h * S_LEN + q) * ROPE_D + i]);
    }
}

// ---------------------------------------------------------------------------
// MLA compressed-space sparse attention. One block (4 waves) per q.
// Wave specialization per 32-key tile: waves 0-1 compute full-576-dim S for
// 16 keys each; waves 2-3 gather/transpose Kpass into KT. 2 barriers/tile.
// Softmax state (m,l) lives in registers (redundant across waves).
// LDS = 36,864 (KT, stride-18 rows) + 2,176 (Ss) = 39 KB -> 4 blocks/CU.
// ---------------------------------------------------------------------------
__global__ __launch_bounds__(256, 4)
void attn_mla(const __hip_bfloat16* __restrict__ Qcat,   // [q][h][576]
              const __hip_bfloat16* __restrict__ kvb,    // [k][576]
              const int* __restrict__ sel_idx,
              __hip_bfloat16* __restrict__ Oc,           // [qloc][h][512]
              int qbase)
{
    __shared__ __align__(16) unsigned int KT[512][18];   // 36,864 B
    __shared__ float Ss[32][17];                         //  2,176 B

    const int q   = blockIdx.x + qbase;
    const int tid = threadIdx.x;
    const int wv  = tid >> 6;
    const int ln  = tid & 63;
    const int g   = ln >> 4;          // 0..3
    const int lo  = ln & 15;
    const int cnt = (q + 1 < TOPK_K) ? (q + 1) : TOPK_K;
    const int* sel = sel_idx + (long)q * TOPK_K;
    const unsigned short* kvu = (const unsigned short*)kvb;
    const unsigned short* qrow = (const unsigned short*)(Qcat + (long)q * NH * CDIM);

    float m_run = -1e30f, l_run = 0.f;
    f32x4 O[8];
    #pragma unroll
    for (int s = 0; s < 8; s++) O[s] = (f32x4){0.f, 0.f, 0.f, 0.f};

    const int ntiles = (cnt + 31) >> 5;

    for (int t = 0; t < ntiles; t++) {
        __syncthreads();   // prev tile's PV done with KT/Ss

        if (wv < 2) {
            // --- S for keys t*32 + wv*16 + lo over all 576 dims (18 MFMA)
            int kidx = t * 32 + wv * 16 + lo;
            int krow = sel[kidx < cnt ? kidx : cnt - 1];
            const unsigned short* kvr = kvu + (long)krow * CDIM + g * 8;
            f32x4 acc = {0.f, 0.f, 0.f, 0.f};
            #pragma unroll
            for (int cc = 0; cc < 18; cc++) {
                s16x8 a = *(const s16x8*)(kvr + cc * 32);
                s16x8 b = *(const s16x8*)&qrow[lo * CDIM + cc * 32 + g * 8];
                acc = __builtin_amdgcn_mfma_f32_16x16x32_bf16(a, b, acc, 0, 0, 0);
            }
            #pragma unroll
            for (int r = 0; r < 4; r++) Ss[wv * 16 + g * 4 + r][lo] = acc[r];
        } else {
            // --- KT staging: wave 2 -> key pairs 0..7, wave 3 -> 8..15
            int pair = (wv - 2) * 8 + (ln & 7);
            int cb = ln >> 3;                 // 0..7
            int k0 = t * 32 + pair * 2, k1 = k0 + 1;
            int r0 = sel[k0 < cnt ? k0 : cnt - 1];
            int r1 = sel[k1 < cnt ? k1 : cnt - 1];
            const unsigned short* p0 = kvu + (long)r0 * CDIM;
            const unsigned short* p1 = kvu + (long)r1 * CDIM;
            #pragma unroll
            for (int u = 0; u < 8; u++) {
                int c = u * 8 + cb;           // 8-dim chunk, 0..63
                u16x8 a0 = *(const u16x8*)(p0 + c * 8);
                u16x8 a1 = *(const u16x8*)(p1 + c * 8);
                #pragma unroll
                for (int d = 0; d < 8; d++)
                    KT[c * 8 + d][pair] = (unsigned)a0[d] | ((unsigned)a1[d] << 16);
            }
        }
        __syncthreads();   // KT + Ss visible

        // --- softmax (all waves redundantly; state in registers)
        float p[8];
        float mx = -1e30f;
        #pragma unroll
        for (int j = 0; j < 8; j++) {
            int kloc = g * 8 + j;
            float s = Ss[kloc][lo] * SCALING;
            if (t * 32 + kloc >= cnt) s = -1e30f;
            p[j] = s;
            mx = fmaxf(mx, s);
        }
        mx = fmaxf(mx, __shfl_xor(mx, 16, 64));
        mx = fmaxf(mx, __shfl_xor(mx, 32, 64));
        float mn = fmaxf(m_run, mx);
        float al = __expf(m_run - mn);
        float sum = 0.f;
        #pragma unroll
        for (int j = 0; j < 8; j++) {
            float e = __expf(p[j] - mn);
            p[j] = e; sum += e;
        }
        sum += __shfl_xor(sum, 16, 64);
        sum += __shfl_xor(sum, 32, 64);
        m_run = mn;
        l_run = l_run * al + sum;

        // --- rescale O (per-head alpha via shfl), then PV MFMA
        float alh[4];
        #pragma unroll
        for (int r = 0; r < 4; r++) alh[r] = __shfl(al, g * 4 + r, 64);
        #pragma unroll
        for (int s = 0; s < 8; s++)
            #pragma unroll
            for (int r = 0; r < 4; r++) O[s][r] *= alh[r];
        union { u16x8 u; s16x8 s; } pw;
        #pragma unroll
        for (int j = 0; j < 8; j++) pw.u[j] = bf16_bits(p[j]);
        #pragma unroll
        for (int s = 0; s < 8; s++) {
            int row = wv * 128 + s * 16 + lo;
            union { unsigned int w[4]; s16x8 v; } bu;
            uint2v x0 = *(const uint2v*)&KT[row][g * 4];
            uint2v x1 = *(const uint2v*)&KT[row][g * 4 + 2];
            bu.w[0] = x0[0]; bu.w[1] = x0[1]; bu.w[2] = x1[0]; bu.w[3] = x1[1];
            O[s] = __builtin_amdgcn_mfma_f32_16x16x32_bf16(pw.s, bu.v, O[s], 0, 0, 0);
        }
    }
    // --- epilogue: divide by l (per-head via shfl), write Oc
    float linv[4];
    #pragma unroll
    for (int r = 0; r < 4; r++) linv[r] = 1.f / __shfl(l_run, g * 4 + r, 64);
    #pragma unroll
    for (int s = 0; s < 8; s++) {
        int dim = wv * 128 + s * 16 + lo;
        #pragma unroll
        for (int r = 0; r < 4; r++) {
            int h = g * 4 + r;
            Oc[((long)blockIdx.x * NH + h) * KV_LORA + dim] = __float2bfloat16(O[s][r] * linv[r]);
        }
    }
}

// ---------------------------------------------------------------------------
// Launch
// ---------------------------------------------------------------------------
extern "C" void kernel_launch(void* const* d_in, const int* in_sizes, int n_in,
                              void* d_out, int out_size, void* d_ws, size_t ws_size,
                              hipStream_t stream)
{
    const float* q_latent = (const float*)d_in[0];   // (2048,1536)
    const float* hidden   = (const float*)d_in[1];   // (2048,2048)
    const float* cosp     = (const float*)d_in[2];   // (2048,64)
    const float* sinp     = (const float*)d_in[3];   // (2048,64)
    const float* q_pass   = (const float*)d_in[4];   // (16,2048,128)
    const float* q_rot    = (const float*)d_in[5];   // (16,2048,64)
    const float* k_pass   = (const float*)d_in[6];   // (2048,512)
    const float* k_rot    = (const float*)d_in[7];   // (2048,64)
    const float* kv_b     = (const float*)d_in[9];   // (4096,512)
    const float* wq_b_w   = (const float*)d_in[10];  // (2048,1536)
    const float* wk_w     = (const float*)d_in[11];  // (128,2048)
    const float* k_norm_w = (const float*)d_in[12];  // (64)
    const float* wproj_w  = (const float*)d_in[13];  // (16,2048)
    const float* wproj_b  = (const float*)d_in[14];  // (16)

    float* ws = (float*)d_ws;
    // Persistent: sel_idx
    int* sel_idx = (int*)ws;                                       // [0 .. 2,097,152)
    // Phase 1a: split inputs for ql GEMM
    unsigned short* qlat_hi = (unsigned short*)(ws + 2097152);
    unsigned short* qlat_lo = (unsigned short*)(ws + 3670016);
    unsigned short* wq_hi   = (unsigned short*)(ws + 5242880);
    unsigned short* wq_lo   = (unsigned short*)(ws + 6815744);     // ends 8,388,608 f
    float* ql = ws + 8388608;                                      // 4,194,304 f -> 12,582,912
    // Phase 1b (after ql GEMM; aliases qlat/wq region):
    unsigned short* iq_hi = (unsigned short*)(ws + 2097152);
    unsigned short* iq_lo = (unsigned short*)(ws + 4194304);
    unsigned short* ik_hi = (unsigned short*)(ws + 6291456);
    unsigned short* ik_lo = (unsigned short*)(ws + 6422528);
    float* wmat = ws + 6553600;                                    // 32,768 f
    float* ckv  = ws + 6586368;                                    // 262,144 f -> 6,848,512
    float* sc   = ws + 8388608;                                    // aliases ql (dead after pack iq)
    float* part = ws + 12582912;                                   // 2,359,296 f -> 14,942,208
    // Phase 2 (after topk; aliases phase-1):
    __hip_bfloat16* Qcat = (__hip_bfloat16*)(ws + 2097152);        // ends f-off 11,534,336
    __hip_bfloat16* kvb  = (__hip_bfloat16*)(ws + 11534336);       // -> 12,124,160
    unsigned short* kbT  = (unsigned short*)(ws + 12124160);       // -> 12,648,448
    unsigned short* vb   = (unsigned short*)(ws + 12648448);       // -> 13,172,736
    unsigned short* qp   = (unsigned short*)(ws + 13172736);       // -> 15,269,888
    __hip_bfloat16* Oc   = (__hip_bfloat16*)(ws + 13172736);       // aliases qp; -> 17,367,040 f

    dim3 b256(256);
    // --- indexer path (split-bf16 MFMA, selection-exact) ---
    pack_split<<<dim3(12288), b256, 0, stream>>>(q_latent, qlat_hi, qlat_lo, 2048L * 1536);
    pack_split<<<dim3(12288), b256, 0, stream>>>(wq_b_w, wq_hi, wq_lo, 2048L * 1536);
    gemm_split3<<<dim3(32, 32), b256, 0, stream>>>(qlat_hi, qlat_lo, wq_hi, wq_lo,
        ql, 2048, 1536, 1536, 1536, 2048);
    rope_iq_inplace<<<dim3(2048, 16), dim3(64), 0, stream>>>(ql, cosp, sinp);
    pack_split<<<dim3(16384), b256, 0, stream>>>(ql, iq_hi, iq_lo, 2048L * 2048);
    // fused hidden projections (ckv 128 cols + wmat 16 cols) via split-K
    proj_splitk<<<dim3(3, 32, 8), b256, 0, stream>>>(hidden, wk_w, wproj_w, part);
    proj_reduce<<<dim3((S_LEN * 144 + 255) / 256), b256, 0, stream>>>(part, ckv, wmat);
    build_ik_inplace<<<dim3(2048), dim3(64), 0, stream>>>(ckv, cosp, sinp, k_norm_w);
    pack_split<<<dim3(1024), b256, 0, stream>>>(ckv, ik_hi, ik_lo, 2048L * 128);
    absbias_inplace<<<dim3(128), b256, 0, stream>>>(wmat, wproj_b);
    scores_mfma<<<dim3(32, 32), b256, 0, stream>>>(iq_hi, iq_lo, ik_hi, ik_lo, wmat, sc);
    topk_kernel<<<dim3(2048), b256, 0, stream>>>(sc, sel_idx);

    // --- attention path (bf16 MFMA, compressed space) ---
    pack_bf16<<<dim3(16384), b256, 0, stream>>>(q_pass, qp, 16L * 2048 * 128);
    pack_kbT<<<dim3(4096), b256, 0, stream>>>(kv_b, kbT);
    pack_vb<<<dim3(4096), b256, 0, stream>>>(kv_b, vb);
    pack_kv<<<dim3(2048), b256, 0, stream>>>(k_pass, k_rot, kvb);
    // q_abs[h] = qp[h] (2048x128) @ kbT[h]^T (512x128): K=128
    gemm_bf16<__hip_bfloat16><<<dim3(8, 32, 16), b256, 0, stream>>>(
        qp, kbT, (__hip_bfloat16*)Qcat, 128, 128, 128, NH * CDIM,
        2048L * 128, 512L * 128, (long)CDIM);
    pack_qrot<<<dim3(2048), b256, 0, stream>>>(q_rot, Qcat);

    // Two q-halves to bound the Oc footprint.
    for (int half = 0; half < 2; half++) {
        int qb = half * 1024;
        attn_mla<<<dim3(1024), b256, 0, stream>>>(Qcat, kvb, sel_idx, Oc, qb);
        // out[q][h][d] = Oc[q][h][:512] . vb[h][d][:512]: K=512 (lda=8192!)
        gemm_bf16<float><<<dim3(2, 16, 16), b256, 0, stream>>>(
            (const unsigned short*)Oc, vb, (float*)d_out + (long)qb * NH * IDIM,
            512, NH * KV_LORA, KV_LORA, NH * IDIM,
            512L, 128L * 512, (long)IDIM);
    }
}

// Round 7
// 1130.116 us; speedup vs baseline: 4.6741x; 1.1396x over previous
//
#include <hip/hip_runtime.h>
#include <hip/hip_bf16.h>

// Problem constants (B=1)
#define S_LEN   2048
#define NH      16
#define ROPE_D  64
#define IDIM    128
#define KV_LORA 512
#define CDIM    576            // KV_LORA + ROPE_D (compressed attention dim)
#define TOPK_K  1024
#define SCALING 0.08838834764831845f   // 128^-0.5

typedef __attribute__((ext_vector_type(4))) float f32x4;
typedef __attribute__((ext_vector_type(8))) short s16x8;
typedef __attribute__((ext_vector_type(8))) unsigned short u16x8;

static __device__ __forceinline__ unsigned short bf16_bits(float v)
{
    __hip_bfloat16 h = __float2bfloat16(v);
    return *(unsigned short*)&h;
}

#define BM 64
#define BN 64
#define BK 16

// ---------------------------------------------------------------------------
// Fused split-K projection: part[ks][m][n] = hidden[m, ks*256:+256] @ W^T
// W rows = [wk_w(128); wproj_w(16)], N=144. grid (3,32,8) = 768 blocks.
// ---------------------------------------------------------------------------
#define PKC 256

__global__ __launch_bounds__(256)
void proj_splitk(const float* __restrict__ hidden, const float* __restrict__ wk_w,
                 const float* __restrict__ wproj_w, float* __restrict__ part)
{
    int nt = blockIdx.x, mt = blockIdx.y, ks = blockIdx.z;
    int n0 = nt * 64, m0 = mt * 64, k00 = ks * PKC;
    __shared__ float As[BK][BM + 1];
    __shared__ float Bs[BK][BN + 1];
    int tid = threadIdx.x, tx = tid & 15, ty = tid >> 4;
    float acc[4][4] = {};
    for (int k0 = 0; k0 < PKC; k0 += BK) {
        for (int t = tid; t < BM * BK; t += 256) {
            int m = t >> 4, kk = t & 15;
            As[kk][m] = hidden[(long)(m0 + m) * 2048 + k00 + k0 + kk];
        }
        for (int t = tid; t < BN * BK; t += 256) {
            int nn = t >> 4, kk = t & 15;
            int n = n0 + nn;
            float v = 0.f;
            if (n < 128)      v = wk_w[(long)n * 2048 + k00 + k0 + kk];
            else if (n < 144) v = wproj_w[(long)(n - 128) * 2048 + k00 + k0 + kk];
            Bs[kk][nn] = v;
        }
        __syncthreads();
        #pragma unroll
        for (int kk = 0; kk < BK; kk++) {
            float a[4], b[4];
            #pragma unroll
            for (int i = 0; i < 4; i++) a[i] = As[kk][ty * 4 + i];
            #pragma unroll
            for (int j = 0; j < 4; j++) b[j] = Bs[kk][tx * 4 + j];
            #pragma unroll
            for (int i = 0; i < 4; i++)
                #pragma unroll
                for (int j = 0; j < 4; j++) acc[i][j] += a[i] * b[j];
        }
        __syncthreads();
    }
    for (int i = 0; i < 4; i++) {
        int m = m0 + ty * 4 + i;
        for (int j = 0; j < 4; j++) {
            int n = n0 + tx * 4 + j;
            if (n < 144) part[((long)ks * S_LEN + m) * 144 + n] = acc[i][j];
        }
    }
}

__global__ void proj_reduce(const float* __restrict__ part, float* __restrict__ ckv,
                            float* __restrict__ wmat)
{
    int i = blockIdx.x * 256 + threadIdx.x;
    if (i >= S_LEN * 144) return;
    int m = i / 144, n = i % 144;
    float s = 0.f;
    #pragma unroll
    for (int ks = 0; ks < 8; ks++) s += part[((long)ks * S_LEN + m) * 144 + n];
    if (n < 128) ckv[(long)m * 128 + n] = s;
    else         wmat[(long)m * 16 + (n - 128)] = s;
}

// ---------------------------------------------------------------------------
// Elementwise packs
// ---------------------------------------------------------------------------
__global__ void pack_split(const float* __restrict__ x, unsigned short* __restrict__ hi,
                           unsigned short* __restrict__ lo, long n)
{
    long i = (long)blockIdx.x * 256 + threadIdx.x;
    if (i < n) {
        float v = x[i];
        __hip_bfloat16 h = __float2bfloat16(v);
        float hv = __bfloat162float(h);
        hi[i] = *(unsigned short*)&h;
        lo[i] = bf16_bits(v - hv);
    }
}

__global__ void pack_bf16(const float* __restrict__ x, unsigned short* __restrict__ y, long n)
{
    long i = (long)blockIdx.x * 256 + threadIdx.x;
    if (i < n) y[i] = bf16_bits(x[i]);
}

// kbT[h][n(512)][k(128)] = kv_b[(h*256 + k)*512 + n]
__global__ void pack_kbT(const float* __restrict__ kv_b, unsigned short* __restrict__ kbT)
{
    long i = (long)blockIdx.x * 256 + threadIdx.x;
    int k = i & 127, n = (i >> 7) & 511, h = i >> 16;
    kbT[i] = bf16_bits(kv_b[((long)h * 256 + k) * 512 + n]);
}

// vb[h][d(128)][r(512)] = kv_b[(h*256+128+d)*512 + r]
__global__ void pack_vb(const float* __restrict__ kv_b, unsigned short* __restrict__ vb)
{
    long i = (long)blockIdx.x * 256 + threadIdx.x;
    int r = i & 511, d = (i >> 9) & 127, h = i >> 16;
    vb[i] = bf16_bits(kv_b[((long)h * 256 + 128 + d) * 512 + r]);
}

// ---------------------------------------------------------------------------
// w = |gemm_out + bias|, in-place
// ---------------------------------------------------------------------------
__global__ void absbias_inplace(float* __restrict__ w, const float* __restrict__ b)
{
    int idx = blockIdx.x * 256 + threadIdx.x;
    if (idx < S_LEN * NH) w[idx] = fabsf(w[idx] + b[idx & 15]);
}

// ---------------------------------------------------------------------------
// In-place interleaved RoPE on ql -> index_q
// ---------------------------------------------------------------------------
__global__ void rope_iq_inplace(float* __restrict__ ql,
                                const float* __restrict__ cosb,
                                const float* __restrict__ sinb)
{
    int s = blockIdx.x, h = blockIdx.y, i = threadIdx.x;   // i in [0,64)
    float* row = ql + (long)s * (NH * IDIM) + h * IDIM;
    float y  = (i < 32) ? row[2 * i]     : row[2 * (i - 32) + 1];
    float yr = (i < 32) ? -row[2 * i + 1] : row[2 * (i - 32)];
    float c  = cosb[s * ROPE_D + i];
    float sn = sinb[s * ROPE_D + i];
    float val = y * c + yr * sn;
    __syncthreads();
    row[i] = val;
}

// ---------------------------------------------------------------------------
// In-place build of index_k from ckv rows
// ---------------------------------------------------------------------------
__global__ void build_ik_inplace(float* __restrict__ ckv,
                                 const float* __restrict__ cosb,
                                 const float* __restrict__ sinb,
                                 const float* __restrict__ knw)
{
    int k = blockIdx.x, i = threadIdx.x;   // i in [0,64)
    float* row = ckv + (long)k * IDIM;
    float y  = (i < 32) ? row[2 * i]     : row[2 * (i - 32) + 1];
    float yr = (i < 32) ? -row[2 * i + 1] : row[2 * (i - 32)];
    float c  = cosb[k * ROPE_D + i];
    float sn = sinb[k * ROPE_D + i];
    float rot = y * c + yr * sn;
    float xp = row[ROPE_D + i];
    float ss = xp * xp;
    for (int off = 32; off; off >>= 1) ss += __shfl_down(ss, off, 64);
    ss = __shfl(ss, 0, 64);
    float nv = xp * rsqrtf(ss / 64.f + 1e-6f) * knw[i];
    __syncthreads();
    row[i] = rot;
    row[ROPE_D + i] = nv;
}

// ---------------------------------------------------------------------------
// Split-bf16 MFMA GEMM: C(fp32) = A @ B^T, A,B given as (hi,lo) bf16 pairs.
// ---------------------------------------------------------------------------
__global__ __launch_bounds__(256)
void gemm_split3(const unsigned short* __restrict__ Ah, const unsigned short* __restrict__ Al,
                 const unsigned short* __restrict__ Bh, const unsigned short* __restrict__ Bl,
                 float* __restrict__ C, int N, int K, int lda, int ldb, int ldc)
{
    int tid = threadIdx.x, wv = tid >> 6, ln = tid & 63, g = ln >> 4, lo = ln & 15;
    int m0 = blockIdx.y * 64 + wv * 16, n0 = blockIdx.x * 64;
    f32x4 acc[4] = {};
    for (int kc = 0; kc < K; kc += 32) {
        long aoff = (long)(m0 + lo) * lda + kc + g * 8;
        s16x8 ah = *(const s16x8*)&Ah[aoff];
        s16x8 al = *(const s16x8*)&Al[aoff];
        #pragma unroll
        for (int nt = 0; nt < 4; nt++) {
            long boff = (long)(n0 + nt * 16 + lo) * ldb + kc + g * 8;
            s16x8 bh = *(const s16x8*)&Bh[boff];
            s16x8 bl = *(const s16x8*)&Bl[boff];
            acc[nt] = __builtin_amdgcn_mfma_f32_16x16x32_bf16(ah, bh, acc[nt], 0, 0, 0);
            acc[nt] = __builtin_amdgcn_mfma_f32_16x16x32_bf16(ah, bl, acc[nt], 0, 0, 0);
            acc[nt] = __builtin_amdgcn_mfma_f32_16x16x32_bf16(al, bh, acc[nt], 0, 0, 0);
        }
    }
    #pragma unroll
    for (int nt = 0; nt < 4; nt++)
        #pragma unroll
        for (int r = 0; r < 4; r++)
            C[(long)(m0 + g * 4 + r) * ldc + n0 + nt * 16 + lo] = acc[nt][r];
}

// ---------------------------------------------------------------------------
// Plain bf16 MFMA GEMM: C = A @ B^T. K explicit (lda may exceed K).
// ---------------------------------------------------------------------------
template<typename TC>
__global__ __launch_bounds__(256)
void gemm_bf16(const unsigned short* __restrict__ A, const unsigned short* __restrict__ B,
               TC* __restrict__ C, int K, int lda, int ldb, int ldc,
               long sA, long sB, long sC)
{
    A += (long)blockIdx.z * sA; B += (long)blockIdx.z * sB; C += (long)blockIdx.z * sC;
    int tid = threadIdx.x, wv = tid >> 6, ln = tid & 63, g = ln >> 4, lo = ln & 15;
    int m0 = blockIdx.y * 64 + wv * 16, n0 = blockIdx.x * 64;
    f32x4 acc[4] = {};
    for (int kc = 0; kc < K; kc += 32) {
        s16x8 a = *(const s16x8*)&A[(long)(m0 + lo) * lda + kc + g * 8];
        #pragma unroll
        for (int nt = 0; nt < 4; nt++) {
            s16x8 b = *(const s16x8*)&B[(long)(n0 + nt * 16 + lo) * ldb + kc + g * 8];
            acc[nt] = __builtin_amdgcn_mfma_f32_16x16x32_bf16(a, b, acc[nt], 0, 0, 0);
        }
    }
    #pragma unroll
    for (int nt = 0; nt < 4; nt++)
        #pragma unroll
        for (int r = 0; r < 4; r++)
            C[(long)(m0 + g * 4 + r) * ldc + n0 + nt * 16 + lo] = (TC)acc[nt][r];
}

// ---------------------------------------------------------------------------
// Indexer scores via split-bf16 MFMA.
// ---------------------------------------------------------------------------
__global__ __launch_bounds__(256)
void scores_mfma(const unsigned short* __restrict__ iq_hi, const unsigned short* __restrict__ iq_lo,
                 const unsigned short* __restrict__ ik_hi, const unsigned short* __restrict__ ik_lo,
                 const float* __restrict__ w, float* __restrict__ sc)
{
    int bk = blockIdx.x, bq = blockIdx.y;
    if (bk > bq) return;
    int q0 = bq * 64, k0 = bk * 64;
    __shared__ __align__(16) unsigned short Khi[64][136];
    __shared__ __align__(16) unsigned short Klo[64][136];
    __shared__ float Ws[64][17];
    int tid = threadIdx.x, wv = tid >> 6, ln = tid & 63, g = ln >> 4, lo = ln & 15;

    for (int i = tid; i < 64 * 16; i += 256) {
        int r = i >> 4, c8 = i & 15;
        *(u16x8*)&Khi[r][c8 * 8] = *(const u16x8*)&ik_hi[(long)(k0 + r) * IDIM + c8 * 8];
        *(u16x8*)&Klo[r][c8 * 8] = *(const u16x8*)&ik_lo[(long)(k0 + r) * IDIM + c8 * 8];
    }
    for (int i = tid; i < 64 * 16; i += 256)
        Ws[i >> 4][i & 15] = w[(long)(q0 + (i >> 4)) * NH + (i & 15)];
    __syncthreads();

    float fin[4][4][4] = {};   // [mt][nt][r]
    #pragma unroll
    for (int hh = 0; hh < 4; hh++) {
        int h = wv * 4 + hh;
        #pragma unroll
        for (int mg = 0; mg < 2; mg++) {
            f32x4 acc[2][4] = {};
            #pragma unroll
            for (int kc = 0; kc < 4; kc++) {
                s16x8 ah[2], al[2];
                #pragma unroll
                for (int mi = 0; mi < 2; mi++) {
                    long off = ((long)(q0 + (mg * 2 + mi) * 16 + lo) * NH + h) * IDIM + kc * 32 + g * 8;
                    ah[mi] = *(const s16x8*)&iq_hi[off];
                    al[mi] = *(const s16x8*)&iq_lo[off];
                }
                #pragma unroll
                for (int nt = 0; nt < 4; nt++) {
                    s16x8 bh = *(const s16x8*)&Khi[nt * 16 + lo][kc * 32 + g * 8];
                    s16x8 bl = *(const s16x8*)&Klo[nt * 16 + lo][kc * 32 + g * 8];
                    #pragma unroll
                    for (int mi = 0; mi < 2; mi++) {
                        acc[mi][nt] = __builtin_amdgcn_mfma_f32_16x16x32_bf16(ah[mi], bh, acc[mi][nt], 0, 0, 0);
                        acc[mi][nt] = __builtin_amdgcn_mfma_f32_16x16x32_bf16(ah[mi], bl, acc[mi][nt], 0, 0, 0);
                        acc[mi][nt] = __builtin_amdgcn_mfma_f32_16x16x32_bf16(al[mi], bh, acc[mi][nt], 0, 0, 0);
                    }
                }
            }
            #pragma unroll
            for (int mi = 0; mi < 2; mi++) {
                int mt = mg * 2 + mi;
                #pragma unroll
                for (int r = 0; r < 4; r++) {
                    float wqh = Ws[mt * 16 + g * 4 + r][h];
                    #pragma unroll
                    for (int nt = 0; nt < 4; nt++) {
                        float v = acc[mi][nt][r] * SCALING;
                        v = v > 0.f ? v : 0.f;
                        fin[mt][nt][r] += v * wqh;
                    }
                }
            }
        }
    }
    __syncthreads();
    float (*FinBuf)[68] = (float(*)[68])&Khi[0][0];
    for (int wt = 0; wt < 4; wt++) {
        if (wv == wt) {
            #pragma unroll
            for (int mt = 0; mt < 4; mt++)
                #pragma unroll
                for (int r = 0; r < 4; r++)
                    #pragma unroll
                    for (int nt = 0; nt < 4; nt++) {
                        if (wt == 0) FinBuf[mt * 16 + g * 4 + r][nt * 16 + lo] = fin[mt][nt][r];
                        else         FinBuf[mt * 16 + g * 4 + r][nt * 16 + lo] += fin[mt][nt][r];
                    }
        }
        __syncthreads();
    }
    for (int i = tid; i < 64 * 16; i += 256) {
        int r = i >> 4, c4 = i & 15;
        *(f32x4*)&sc[(long)(q0 + r) * S_LEN + k0 + c4 * 4] = *(f32x4*)&FinBuf[r][c4 * 4];
    }
}

// ---------------------------------------------------------------------------
// Exact top-1024 per row via radix-select on float bits (scores >= 0).
// ---------------------------------------------------------------------------
__device__ __forceinline__ int block_scan_excl(int v, volatile int* lds, int tid, int* total)
{
    lds[tid] = v;
    __syncthreads();
    int x = v;
    for (int off = 1; off < 256; off <<= 1) {
        int y = (tid >= off) ? lds[tid - off] : 0;
        __syncthreads();
        x += y;
        lds[tid] = x;
        __syncthreads();
    }
    int t = lds[255];
    __syncthreads();
    *total = t;
    return x - v;
}

__global__ __launch_bounds__(256)
void topk_kernel(const float* __restrict__ sc, int* __restrict__ sel_idx)
{
    __shared__ int lds[256];
    __shared__ int wsum[4];
    int q = blockIdx.x, tid = threadIdx.x;
    int n = q + 1;
    int* row_sel = sel_idx + (long)q * TOPK_K;
    if (n <= TOPK_K) {
        for (int i = tid; i < n; i += 256) row_sel[i] = i;
        return;
    }
    const float* row = sc + (long)q * S_LEN;
    unsigned bits[8];
    int base = tid * 8;
    #pragma unroll
    for (int i = 0; i < 8; i++) {
        int k = base + i;
        bits[i] = (k < n) ? __float_as_uint(row[k]) : 0u;
    }
    unsigned prefix = 0;
    for (int bit = 30; bit >= 0; bit--) {
        unsigned cand = prefix | (1u << bit);
        int c = 0;
        #pragma unroll
        for (int i = 0; i < 8; i++) c += (bits[i] >= cand) ? 1 : 0;
        for (int off = 32; off; off >>= 1) c += __shfl_down(c, off, 64);
        if ((tid & 63) == 0) wsum[tid >> 6] = c;
        __syncthreads();
        int total = wsum[0] + wsum[1] + wsum[2] + wsum[3];
        __syncthreads();
        if (total >= TOPK_K) prefix = cand;
    }
    unsigned v = prefix;
    int lgt = 0, leq = 0;
    #pragma unroll
    for (int i = 0; i < 8; i++) {
        int k = base + i;
        if (k >= n) break;
        if (bits[i] > v) lgt++;
        else if (bits[i] == v) leq++;
    }
    int tot_gt, tot_eq;
    int gt_off = block_scan_excl(lgt, lds, tid, &tot_gt);
    int eq_off = block_scan_excl(leq, lds, tid, &tot_eq);
    int fill = TOPK_K - tot_gt;
    int gpos = gt_off, epos = eq_off;
    for (int i = 0; i < 8; i++) {
        int k = base + i;
        if (k >= n) break;
        if (bits[i] > v) {
            row_sel[gpos++] = k;
        } else if (bits[i] == v) {
            if (epos < fill) row_sel[tot_gt + epos] = k;
            epos++;
        }
    }
}

// ---------------------------------------------------------------------------
// bf16 packs for the attention path
// ---------------------------------------------------------------------------
__global__ void pack_kv(const float* __restrict__ k_pass, const float* __restrict__ k_rot,
                        __hip_bfloat16* __restrict__ kvb)
{
    int k = blockIdx.x;
    for (int i = threadIdx.x; i < CDIM; i += 256) {
        float v = (i < KV_LORA) ? k_pass[(long)k * KV_LORA + i]
                                : k_rot[(long)k * ROPE_D + (i - KV_LORA)];
        kvb[(long)k * CDIM + i] = __float2bfloat16(v);
    }
}

__global__ void pack_qrot(const float* __restrict__ q_rot, __hip_bfloat16* __restrict__ Qcat)
{
    int q = blockIdx.x;
    for (int j = threadIdx.x; j < NH * ROPE_D; j += 256) {
        int h = j >> 6, i = j & 63;
        Qcat[((long)q * NH + h) * CDIM + KV_LORA + i] =
            __float2bfloat16(q_rot[((long)h * S_LEN + q) * ROPE_D + i]);
    }
}

// ---------------------------------------------------------------------------
// MLA compressed-space sparse attention, barrier-free: ONE WAVE PER QUERY.
// 64-thr blocks, 2048 blocks, ~18.2 KB LDS/block -> 8 blocks/CU, all waves
// fully independent (no __syncthreads anywhere in the loop).
// Per 32-key super-tile:
//   S: two 16-key sub-tiles, keys on m (lane&15=key), 18 MFMA each, A-frags
//      gathered straight from global (quad g supplies dims g*8+j).
//   online softmax in-registers (head = lane&15, shfl_xor 16/32 only).
//   P -> A-layout via private Pb LDS round-trip (2 u32 writes + 1 b128 read).
//   PV in two 256-dim passes: K^T pair-packed into private KT (128 u32 writes
//      per lane per tile), 16 MFMA (K=32) per pass reading b128 B-frags.
// Output O (fp32, 128 VGPRs) is written over the block's OWN Qcat row
// (16x512 bf16 fits inside the 16x576 row) -> no separate Oc buffer.
// ---------------------------------------------------------------------------
__global__ __launch_bounds__(64, 2)
void attn_mla2(const __hip_bfloat16* __restrict__ Qcat,
               const __hip_bfloat16* __restrict__ kvb,
               const int* __restrict__ sel_idx,
               unsigned short* __restrict__ Oout)   // == (unsigned short*)Qcat
{
    __shared__ __align__(16) unsigned int KT[32 * 132];   // 16,896 B
    __shared__ __align__(16) unsigned int Pb[16 * 20];    //  1,280 B

    const int q  = blockIdx.x;
    const int ln = threadIdx.x;          // 0..63
    const int g  = ln >> 4, lo = ln & 15;
    const int pr = ln & 15, cb = ln >> 4;   // staging roles: key-pair, chunk-slot
    const int cnt = (q + 1 < TOPK_K) ? (q + 1) : TOPK_K;
    const int* sel = sel_idx + (long)q * TOPK_K;
    const unsigned short* kvu = (const unsigned short*)kvb;
    const unsigned short* qrow = (const unsigned short*)Qcat + (long)q * NH * CDIM;

    float m_run = -1e30f, l_run = 0.f;
    f32x4 O[32];
    #pragma unroll
    for (int s = 0; s < 32; s++) O[s] = (f32x4){0.f, 0.f, 0.f, 0.f};

    const int ntl = (cnt + 31) >> 5;
    for (int t = 0; t < ntl; t++) {
        const int kb = t * 32;
        // --- S over 32 keys: two 16-key sub-tiles, full 576 dims each
        f32x4 S[2];
        #pragma unroll
        for (int a = 0; a < 2; a++) {
            int kidx = kb + a * 16 + lo;
            int krow = sel[kidx < cnt ? kidx : cnt - 1];
            const unsigned short* kvr = kvu + (long)krow * CDIM + g * 8;
            f32x4 acc = {0.f, 0.f, 0.f, 0.f};
            #pragma unroll
            for (int cc = 0; cc < 18; cc++) {
                s16x8 av = *(const s16x8*)(kvr + cc * 32);
                s16x8 bv = *(const s16x8*)(qrow + lo * CDIM + cc * 32 + g * 8);
                acc = __builtin_amdgcn_mfma_f32_16x16x32_bf16(av, bv, acc, 0, 0, 0);
            }
            S[a] = acc;
        }
        // --- online softmax over 32 keys (head = lo, replicated across quads)
        float pv[8];
        float mx = -1e30f;
        #pragma unroll
        for (int a = 0; a < 2; a++)
            #pragma unroll
            for (int r = 0; r < 4; r++) {
                float s = S[a][r] * SCALING;
                if (kb + a * 16 + g * 4 + r >= cnt) s = -1e30f;
                pv[a * 4 + r] = s;
                mx = fmaxf(mx, s);
            }
        mx = fmaxf(mx, __shfl_xor(mx, 16, 64));
        mx = fmaxf(mx, __shfl_xor(mx, 32, 64));
        float mn = fmaxf(m_run, mx);
        float al = __expf(m_run - mn);
        float sum = 0.f;
        #pragma unroll
        for (int j = 0; j < 8; j++) { float e = __expf(pv[j] - mn); pv[j] = e; sum += e; }
        sum += __shfl_xor(sum, 16, 64);
        sum += __shfl_xor(sum, 32, 64);
        m_run = mn;
        l_run = l_run * al + sum;

        // --- stage P into A-layout: Pb[head][key-pair] (keys kb+2*pair, +1)
        #pragma unroll
        for (int a = 0; a < 2; a++) {
            unsigned w0 = (unsigned)bf16_bits(pv[a * 4 + 0]) | ((unsigned)bf16_bits(pv[a * 4 + 1]) << 16);
            unsigned w1 = (unsigned)bf16_bits(pv[a * 4 + 2]) | ((unsigned)bf16_bits(pv[a * 4 + 3]) << 16);
            Pb[lo * 20 + a * 8 + g * 2]     = w0;
            Pb[lo * 20 + a * 8 + g * 2 + 1] = w1;
        }
        // --- rescale O by per-head alpha
        float alh[4];
        #pragma unroll
        for (int r = 0; r < 4; r++) alh[r] = __shfl(al, g * 4 + r, 64);
        #pragma unroll
        for (int s = 0; s < 32; s++) {
            O[s][0] *= alh[0]; O[s][1] *= alh[1]; O[s][2] *= alh[2]; O[s][3] *= alh[3];
        }
        s16x8 pa = *(const s16x8*)&Pb[lo * 20 + g * 4];

        // --- PV in two 256-dim passes; K^T staged per pass into private KT
        int i0 = kb + 2 * pr, i1 = i0 + 1;
        int r0 = sel[i0 < cnt ? i0 : cnt - 1];
        int r1 = sel[i1 < cnt ? i1 : cnt - 1];
        const unsigned short* p0 = kvu + (long)r0 * CDIM;
        const unsigned short* p1 = kvu + (long)r1 * CDIM;
        #pragma unroll
        for (int P = 0; P < 2; P++) {
            #pragma unroll
            for (int u = 0; u < 8; u++) {
                int cl = u * 4 + cb;            // 0..31 (local 8-dim chunk)
                int cg = P * 32 + cl;           // 0..63 (global chunk, pass dims only)
                u16x8 a0 = *(const u16x8*)(p0 + cg * 8);
                u16x8 a1 = *(const u16x8*)(p1 + cg * 8);
                #pragma unroll
                for (int d = 0; d < 8; d++)
                    KT[cl * 132 + d * 16 + pr] = (unsigned)a0[d] | ((unsigned)a1[d] << 16);
            }
            #pragma unroll
            for (int s = 0; s < 16; s++) {
                int c = s * 2 + (lo >> 3), d = lo & 7;
                s16x8 bf = *(const s16x8*)&KT[c * 132 + d * 16 + g * 4];
                O[P * 16 + s] = __builtin_amdgcn_mfma_f32_16x16x32_bf16(pa, bf, O[P * 16 + s], 0, 0, 0);
            }
        }
    }
    // --- epilogue: O / l -> bf16, written over this block's own Qcat row
    float linv[4];
    #pragma unroll
    for (int r = 0; r < 4; r++) linv[r] = 1.f / __shfl(l_run, g * 4 + r, 64);
    unsigned short* orow = Oout + (long)q * NH * CDIM;
    #pragma unroll
    for (int s = 0; s < 32; s++)
        #pragma unroll
        for (int r = 0; r < 4; r++)
            orow[(g * 4 + r) * KV_LORA + s * 16 + lo] = bf16_bits(O[s][r] * linv[r]);
}

// ---------------------------------------------------------------------------
// Launch
// ---------------------------------------------------------------------------
extern "C" void kernel_launch(void* const* d_in, const int* in_sizes, int n_in,
                              void* d_out, int out_size, void* d_ws, size_t ws_size,
                              hipStream_t stream)
{
    const float* q_latent = (const float*)d_in[0];   // (2048,1536)
    const float* hidden   = (const float*)d_in[1];   // (2048,2048)
    const float* cosp     = (const float*)d_in[2];   // (2048,64)
    const float* sinp     = (const float*)d_in[3];   // (2048,64)
    const float* q_pass   = (const float*)d_in[4];   // (16,2048,128)
    const float* q_rot    = (const float*)d_in[5];   // (16,2048,64)
    const float* k_pass   = (const float*)d_in[6];   // (2048,512)
    const float* k_rot    = (const float*)d_in[7];   // (2048,64)
    const float* kv_b     = (const float*)d_in[9];   // (4096,512)
    const float* wq_b_w   = (const float*)d_in[10];  // (2048,1536)
    const float* wk_w     = (const float*)d_in[11];  // (128,2048)
    const float* k_norm_w = (const float*)d_in[12];  // (64)
    const float* wproj_w  = (const float*)d_in[13];  // (16,2048)
    const float* wproj_b  = (const float*)d_in[14];  // (16)

    float* ws = (float*)d_ws;
    // Persistent: sel_idx
    int* sel_idx = (int*)ws;                                       // [0 .. 2,097,152)
    // Phase 1a: split inputs for ql GEMM
    unsigned short* qlat_hi = (unsigned short*)(ws + 2097152);
    unsigned short* qlat_lo = (unsigned short*)(ws + 3670016);
    unsigned short* wq_hi   = (unsigned short*)(ws + 5242880);
    unsigned short* wq_lo   = (unsigned short*)(ws + 6815744);     // ends 8,388,608 f
    float* ql = ws + 8388608;                                      // 4,194,304 f -> 12,582,912
    // Phase 1b (after ql GEMM; aliases qlat/wq region):
    unsigned short* iq_hi = (unsigned short*)(ws + 2097152);
    unsigned short* iq_lo = (unsigned short*)(ws + 4194304);
    unsigned short* ik_hi = (unsigned short*)(ws + 6291456);
    unsigned short* ik_lo = (unsigned short*)(ws + 6422528);
    float* wmat = ws + 6553600;                                    // 32,768 f
    float* ckv  = ws + 6586368;                                    // 262,144 f -> 6,848,512
    float* sc   = ws + 8388608;                                    // aliases ql (dead after pack iq)
    float* part = ws + 12582912;                                   // 2,359,296 f -> 14,942,208 (phase 1 only)
    // Phase 2 (after topk; aliases phase-1):
    __hip_bfloat16* Qcat = (__hip_bfloat16*)(ws + 2097152);        // ends f-off 11,534,336; Oc written in-place
    __hip_bfloat16* kvb  = (__hip_bfloat16*)(ws + 11534336);       // -> 12,124,160
    unsigned short* kbT  = (unsigned short*)(ws + 12124160);       // -> 12,648,448
    unsigned short* vb   = (unsigned short*)(ws + 12648448);       // -> 13,172,736
    unsigned short* qp   = (unsigned short*)(ws + 13172736);       // -> 15,269,888  (61.1 MB peak)

    dim3 b256(256);
    // --- indexer path (split-bf16 MFMA, selection-exact) ---
    pack_split<<<dim3(12288), b256, 0, stream>>>(q_latent, qlat_hi, qlat_lo, 2048L * 1536);
    pack_split<<<dim3(12288), b256, 0, stream>>>(wq_b_w, wq_hi, wq_lo, 2048L * 1536);
    gemm_split3<<<dim3(32, 32), b256, 0, stream>>>(qlat_hi, qlat_lo, wq_hi, wq_lo,
        ql, 2048, 1536, 1536, 1536, 2048);
    rope_iq_inplace<<<dim3(2048, 16), dim3(64), 0, stream>>>(ql, cosp, sinp);
    pack_split<<<dim3(16384), b256, 0, stream>>>(ql, iq_hi, iq_lo, 2048L * 2048);
    proj_splitk<<<dim3(3, 32, 8), b256, 0, stream>>>(hidden, wk_w, wproj_w, part);
    proj_reduce<<<dim3((S_LEN * 144 + 255) / 256), b256, 0, stream>>>(part, ckv, wmat);
    build_ik_inplace<<<dim3(2048), dim3(64), 0, stream>>>(ckv, cosp, sinp, k_norm_w);
    pack_split<<<dim3(1024), b256, 0, stream>>>(ckv, ik_hi, ik_lo, 2048L * 128);
    absbias_inplace<<<dim3(128), b256, 0, stream>>>(wmat, wproj_b);
    scores_mfma<<<dim3(32, 32), b256, 0, stream>>>(iq_hi, iq_lo, ik_hi, ik_lo, wmat, sc);
    topk_kernel<<<dim3(2048), b256, 0, stream>>>(sc, sel_idx);

    // --- attention path (bf16 MFMA, compressed space) ---
    pack_bf16<<<dim3(16384), b256, 0, stream>>>(q_pass, qp, 16L * 2048 * 128);
    pack_kbT<<<dim3(4096), b256, 0, stream>>>(kv_b, kbT);
    pack_vb<<<dim3(4096), b256, 0, stream>>>(kv_b, vb);
    pack_kv<<<dim3(2048), b256, 0, stream>>>(k_pass, k_rot, kvb);
    // q_abs[h] = qp[h] (2048x128) @ kbT[h]^T (512x128): K=128 -> Qcat[:, h, 0:512]
    gemm_bf16<__hip_bfloat16><<<dim3(8, 32, 16), b256, 0, stream>>>(
        qp, kbT, (__hip_bfloat16*)Qcat, 128, 128, 128, NH * CDIM,
        2048L * 128, 512L * 128, (long)CDIM);
    pack_qrot<<<dim3(2048), b256, 0, stream>>>(q_rot, Qcat);

    // Barrier-free attention: one wave per q, single launch over all 2048 q.
    // O is written over each block's own Qcat row (heads at stride 512).
    attn_mla2<<<dim3(2048), dim3(64), 0, stream>>>(Qcat, kvb, sel_idx,
                                                   (unsigned short*)Qcat);
    // out[q][h][d] = O[q][h][:512] . vb[h][d][:512]; O rows live inside Qcat
    // (row stride NH*CDIM=9216, head offset h*512).
    gemm_bf16<float><<<dim3(2, 32, 16), b256, 0, stream>>>(
        (const unsigned short*)Qcat, vb, (float*)d_out,
        512, NH * CDIM, KV_LORA, NH * IDIM,
        512L, 128L * 512, (long)IDIM);
}